// Round 2
// baseline (5996.704 us; speedup 1.0000x reference)
//
#include <hip/hip_runtime.h>

typedef unsigned short u16;

#define B_    128
#define N0_   320
#define C_    512
#define NH_   8
#define HD_   64
#define NTOK  324
#define H_    18
#define AG_   144
#define SCALE 0.125f

__device__ __forceinline__ float bfu2f(u16 u) {
  union { unsigned int u; float f; } v; v.u = ((unsigned int)u) << 16; return v.f;
}
__device__ __forceinline__ u16 f2bfu(float f) {
  union { float f; unsigned int u; } v; v.f = f;
  unsigned int r = v.u + 0x7fffu + ((v.u >> 16) & 1u);
  return (u16)(r >> 16);
}
__device__ __forceinline__ float wredmax(float v) {
  #pragma unroll
  for (int o = 32; o; o >>= 1) v = fmaxf(v, __shfl_xor(v, o));
  return v;
}
__device__ __forceinline__ float wredsum(float v) {
  #pragma unroll
  for (int o = 32; o; o >>= 1) v += __shfl_xor(v, o);
  return v;
}

// ---------------------------------------------------------------------------
// Bias precompute: bAN[h][a][n] = bilinear(an_bias)[h,a,y,x] + ah[h,a,y] + aw[h,a,x]
//                  bNA[h][n][a] = bilinear(na_bias)[h,a,y,x] + ha[h,y,a] + wa[h,x,a]
// jax.image.resize bilinear (upsample 7->18) == half-pixel coords clamped to [0,6]
// ---------------------------------------------------------------------------
__global__ void bias_kernel(const float* __restrict__ an, const float* __restrict__ na,
                            const float* __restrict__ ah, const float* __restrict__ aw,
                            const float* __restrict__ ha, const float* __restrict__ wa,
                            float* __restrict__ bAN, float* __restrict__ bNA)
{
  const int blk = blockIdx.x;            // h*144 + a
  const int h = blk / AG_, a = blk - h * AG_;
  const int tid = threadIdx.x;
  if (tid >= NTOK) return;
  const int y = tid / H_, x = tid - y * H_;
  float cy = (y + 0.5f) * (7.0f / 18.0f) - 0.5f; cy = fminf(fmaxf(cy, 0.f), 6.f);
  float cx = (x + 0.5f) * (7.0f / 18.0f) - 0.5f; cx = fminf(fmaxf(cx, 0.f), 6.f);
  const int y0 = (int)floorf(cy); const float ty = cy - y0; const int y1 = min(y0 + 1, 6);
  const int x0 = (int)floorf(cx); const float tx = cx - x0; const int x1 = min(x0 + 1, 6);
  const float w00 = (1.f - ty) * (1.f - tx), w01 = (1.f - ty) * tx;
  const float w10 = ty * (1.f - tx), w11 = ty * tx;
  const float* anp = an + (size_t)blk * 49;
  const float* nap = na + (size_t)blk * 49;
  const float van = w00 * anp[y0*7+x0] + w01 * anp[y0*7+x1] + w10 * anp[y1*7+x0] + w11 * anp[y1*7+x1];
  const float vna = w00 * nap[y0*7+x0] + w01 * nap[y0*7+x1] + w10 * nap[y1*7+x0] + w11 * nap[y1*7+x1];
  bAN[(size_t)blk * NTOK + tid] = van + ah[(size_t)blk * H_ + y] + aw[(size_t)blk * H_ + x];
  bNA[((size_t)h * NTOK + tid) * AG_ + a] =
      vna + ha[((size_t)h * H_ + y) * AG_ + a] + wa[((size_t)h * H_ + x) * AG_ + a];
}

// ---------------------------------------------------------------------------
// QKV GEMM: (B*324, 512) x (512, 1536) -> q/k/v bf16 in [b][h][t][d] layout.
// Pad tokens (t<2 || t>=322) read as zero (reference pads x by 2 tokens/side).
// 64x64 tile, BK=16, 256 threads, 4x4 per thread.
// ---------------------------------------------------------------------------
__global__ __launch_bounds__(256) void gemm_qkv(
    const float* __restrict__ x, const float* __restrict__ w,
    u16* __restrict__ qb, u16* __restrict__ kb, u16* __restrict__ vb)
{
  __shared__ float As[16][64];
  __shared__ float Bs[16][64];
  const int bn = blockIdx.x;     // 0..23  (N fast for L2 reuse of x rows)
  const int bm = blockIdx.y;     // 0..647
  const int tid = threadIdx.x;
  const int tx = tid & 15, ty = tid >> 4;

  const int arow = bm * 64 + (tid >> 2);
  const int ab = arow / NTOK;
  const int at = arow - ab * NTOK;
  const float* aptr = nullptr;
  if (at >= 2 && at < 322)
    aptr = x + ((size_t)(ab * N0_ + (at - 2))) * C_ + ((tid & 3) * 4);
  const float* bptr = w + (size_t)(tid >> 4) * 1536 + bn * 64 + ((tid & 15) * 4);

  float acc[4][4] = {};
  for (int k0 = 0; k0 < 512; k0 += 16) {
    float4 ga4 = make_float4(0.f, 0.f, 0.f, 0.f);
    if (aptr) ga4 = *(const float4*)(aptr + k0);
    const float4 gb4 = *(const float4*)(bptr + (size_t)k0 * 1536);
    __syncthreads();
    As[(tid & 3) * 4 + 0][tid >> 2] = ga4.x;
    As[(tid & 3) * 4 + 1][tid >> 2] = ga4.y;
    As[(tid & 3) * 4 + 2][tid >> 2] = ga4.z;
    As[(tid & 3) * 4 + 3][tid >> 2] = ga4.w;
    *(float4*)&Bs[tid >> 4][(tid & 15) * 4] = gb4;
    __syncthreads();
    #pragma unroll
    for (int kk = 0; kk < 16; ++kk) {
      const float4 a4 = *(const float4*)&As[kk][ty * 4];
      const float4 b4 = *(const float4*)&Bs[kk][tx * 4];
      acc[0][0] += a4.x*b4.x; acc[0][1] += a4.x*b4.y; acc[0][2] += a4.x*b4.z; acc[0][3] += a4.x*b4.w;
      acc[1][0] += a4.y*b4.x; acc[1][1] += a4.y*b4.y; acc[1][2] += a4.y*b4.z; acc[1][3] += a4.y*b4.w;
      acc[2][0] += a4.z*b4.x; acc[2][1] += a4.z*b4.y; acc[2][2] += a4.z*b4.z; acc[2][3] += a4.z*b4.w;
      acc[3][0] += a4.w*b4.x; acc[3][1] += a4.w*b4.y; acc[3][2] += a4.w*b4.z; acc[3][3] += a4.w*b4.w;
    }
  }
  const int mat = bn >> 3, h = bn & 7;
  u16* outp = (mat == 0) ? qb : (mat == 1) ? kb : vb;
  #pragma unroll
  for (int i = 0; i < 4; ++i) {
    const int r = bm * 64 + ty * 4 + i;
    const int b = r / NTOK, t = r - b * NTOK;
    ushort4 u;
    u.x = f2bfu(acc[i][0]); u.y = f2bfu(acc[i][1]); u.z = f2bfu(acc[i][2]); u.w = f2bfu(acc[i][3]);
    *(ushort4*)&outp[(((size_t)(b * NH_ + h)) * NTOK + t) * HD_ + tx * 4] = u;
  }
}

// ---------------------------------------------------------------------------
// Adaptive pool q (18x18 -> 12x12): every window is exactly 2x2 (avg of 4).
// ---------------------------------------------------------------------------
__global__ __launch_bounds__(512) void pool_kernel(const u16* __restrict__ qb, u16* __restrict__ agb)
{
  const int blk = blockIdx.x;           // b*144 + a
  const int b = blk / AG_, a = blk - b * AG_;
  const int o = a / 12, pc = a - o * 12;
  const int y0 = (3 * o) >> 1, x0 = (3 * pc) >> 1;
  const int c = threadIdx.x; const int h = c >> 6, d = c & 63;
  const size_t base = ((size_t)(b * NH_ + h)) * NTOK * HD_ + d;
  const int t00 = (y0 * H_ + x0) * HD_;
  const float v = bfu2f(qb[base + t00]) + bfu2f(qb[base + t00 + HD_])
                + bfu2f(qb[base + t00 + H_ * HD_]) + bfu2f(qb[base + t00 + H_ * HD_ + HD_]);
  agb[((size_t)(b * NH_ + h)) * AG_ * HD_ + a * HD_ + d] = f2bfu(0.25f * v);
}

// ---------------------------------------------------------------------------
// Stage 1: agent_attn = softmax(scale*ag . k + biasAN); agent_v = attn @ v
// Block per (b,h): k,v staged in LDS (row pad 68 u16 -> 2-way banks = free).
// ---------------------------------------------------------------------------
__global__ __launch_bounds__(384) void stage1_kernel(
    const u16* __restrict__ kb, const u16* __restrict__ vb,
    const u16* __restrict__ agb, const float* __restrict__ bAN,
    u16* __restrict__ avb)
{
  __shared__ u16 kL[NTOK * 68];
  __shared__ u16 vL[NTOK * 68];
  __shared__ float agL[64];
  __shared__ float p[NTOK];
  __shared__ float part[384];
  __shared__ float red[2];
  const int bh = blockIdx.x;
  const int h = bh & 7;
  const int tid = threadIdx.x;
  const ushort4* kg = (const ushort4*)(kb + (size_t)bh * NTOK * HD_);
  const ushort4* vg = (const ushort4*)(vb + (size_t)bh * NTOK * HD_);
  for (int idx = tid; idx < NTOK * 16; idx += 384) {
    const int n = idx >> 4, c4 = idx & 15;
    *(ushort4*)&kL[n * 68 + c4 * 4] = kg[idx];
    *(ushort4*)&vL[n * 68 + c4 * 4] = vg[idx];
  }
  __syncthreads();
  const float* bANh = bAN + (size_t)h * AG_ * NTOK;
  const int g = tid >> 6, d = tid & 63;
  for (int a = 0; a < AG_; ++a) {
    if (tid < 64) agL[tid] = SCALE * bfu2f(agb[((size_t)bh * AG_ + a) * HD_ + tid]);
    __syncthreads();
    float s = 0.f;
    if (tid < NTOK) {
      const u16* kr = &kL[tid * 68];
      float acc = 0.f;
      #pragma unroll
      for (int d8 = 0; d8 < 64; d8 += 8) {
        const ushort4 u0 = *(const ushort4*)&kr[d8];
        const ushort4 u1 = *(const ushort4*)&kr[d8 + 4];
        const float4 a0 = *(const float4*)&agL[d8];
        const float4 a1 = *(const float4*)&agL[d8 + 4];
        acc += a0.x*bfu2f(u0.x) + a0.y*bfu2f(u0.y) + a0.z*bfu2f(u0.z) + a0.w*bfu2f(u0.w)
             + a1.x*bfu2f(u1.x) + a1.y*bfu2f(u1.y) + a1.z*bfu2f(u1.z) + a1.w*bfu2f(u1.w);
      }
      s = acc + bANh[a * NTOK + tid];
      p[tid] = s;
    }
    __syncthreads();
    if (tid < 64) {
      float m = -1e30f;
      for (int i = tid; i < NTOK; i += 64) m = fmaxf(m, p[i]);
      m = wredmax(m);
      if (tid == 0) red[0] = m;
    }
    __syncthreads();
    const float M = red[0];
    if (tid < NTOK) p[tid] = __expf(s - M);
    __syncthreads();
    if (tid < 64) {
      float sm = 0.f;
      for (int i = tid; i < NTOK; i += 64) sm += p[i];
      sm = wredsum(sm);
      if (tid == 0) red[1] = 1.0f / sm;
    }
    __syncthreads();
    const float inv = red[1];
    float acc = 0.f;
    for (int n = g; n < NTOK; n += 6) acc += p[n] * bfu2f(vL[n * 68 + d]);
    part[tid] = acc;
    __syncthreads();
    if (tid < 64) {
      const float o = part[tid] + part[tid+64] + part[tid+128] + part[tid+192] + part[tid+256] + part[tid+320];
      avb[((size_t)bh * AG_ + a) * HD_ + tid] = f2bfu(o * inv);
    }
    __syncthreads();
  }
}

// ---------------------------------------------------------------------------
// Stage 2 + fused depthwise conv:
// q_attn = softmax(scale*q . ag + biasNA); out_h = q_attn @ agent_v ; += dwc(v)
// Block per (b, h, t-chunk of 80). ag/agent_v staged in LDS.
// Writes attn_out (aliases dead k buffer) in [b][t][c] bf16.
// ---------------------------------------------------------------------------
__global__ __launch_bounds__(256) void stage2_kernel(
    const u16* __restrict__ qb, const u16* __restrict__ agb,
    const u16* __restrict__ avb, const u16* __restrict__ vb,
    const float* __restrict__ bNA, const float* __restrict__ dwc_w,
    const float* __restrict__ dwc_b, u16* __restrict__ aob)
{
  __shared__ u16 agL[AG_ * 68];
  __shared__ u16 avL[AG_ * 68];
  __shared__ float qL[64];
  __shared__ float p[AG_];
  __shared__ float part[256];
  __shared__ float red[2];
  const int b = blockIdx.x, h = blockIdx.y, chunk = blockIdx.z;
  const int bh = b * NH_ + h;
  const int tid = threadIdx.x;
  const ushort4* ag_g = (const ushort4*)(agb + (size_t)bh * AG_ * HD_);
  const ushort4* av_g = (const ushort4*)(avb + (size_t)bh * AG_ * HD_);
  for (int idx = tid; idx < AG_ * 16; idx += 256) {
    const int n = idx >> 4, c4 = idx & 15;
    *(ushort4*)&agL[n * 68 + c4 * 4] = ag_g[idx];
    *(ushort4*)&avL[n * 68 + c4 * 4] = av_g[idx];
  }
  const int g = tid >> 6, d = tid & 63;
  float w9[9]; float cb = 0.f;
  if (tid < 64) {
    #pragma unroll
    for (int j = 0; j < 9; ++j) w9[j] = dwc_w[(size_t)(h * 64 + tid) * 9 + j];
    cb = dwc_b[h * 64 + tid];
  }
  __syncthreads();
  for (int i = 0; i < 80; ++i) {
    const int t = 2 + chunk * 80 + i;
    if (tid < 64) qL[tid] = SCALE * bfu2f(qb[((size_t)bh * NTOK + t) * HD_ + tid]);
    __syncthreads();
    float s = 0.f;
    if (tid < AG_) {
      const u16* ar = &agL[tid * 68];
      float acc = 0.f;
      #pragma unroll
      for (int d8 = 0; d8 < 64; d8 += 8) {
        const ushort4 u0 = *(const ushort4*)&ar[d8];
        const ushort4 u1 = *(const ushort4*)&ar[d8 + 4];
        const float4 a0 = *(const float4*)&qL[d8];
        const float4 a1 = *(const float4*)&qL[d8 + 4];
        acc += a0.x*bfu2f(u0.x) + a0.y*bfu2f(u0.y) + a0.z*bfu2f(u0.z) + a0.w*bfu2f(u0.w)
             + a1.x*bfu2f(u1.x) + a1.y*bfu2f(u1.y) + a1.z*bfu2f(u1.z) + a1.w*bfu2f(u1.w);
      }
      s = acc + bNA[((size_t)h * NTOK + t) * AG_ + tid];
      p[tid] = s;
    }
    __syncthreads();
    if (tid < 64) {
      float m = fmaxf(p[tid], p[tid + 64]);
      if (tid < 16) m = fmaxf(m, p[tid + 128]);
      m = wredmax(m);
      if (tid == 0) red[0] = m;
    }
    __syncthreads();
    const float M = red[0];
    if (tid < AG_) p[tid] = __expf(s - M);
    __syncthreads();
    if (tid < 64) {
      float sm = p[tid] + p[tid + 64] + ((tid < 16) ? p[tid + 128] : 0.f);
      sm = wredsum(sm);
      if (tid == 0) red[1] = 1.0f / sm;
    }
    __syncthreads();
    const float inv = red[1];
    float acc = 0.f;
    for (int a = g; a < AG_; a += 4) acc += p[a] * bfu2f(avL[a * 68 + d]);
    part[tid] = acc;
    __syncthreads();
    if (tid < 64) {
      float o = (part[tid] + part[tid + 64] + part[tid + 128] + part[tid + 192]) * inv;
      const int y = t / H_, xx = t - y * H_;
      float conv = cb;
      #pragma unroll
      for (int ky = 0; ky < 3; ++ky) {
        const int yy = y + ky - 1;
        if (yy < 0 || yy >= H_) continue;
        #pragma unroll
        for (int kx = 0; kx < 3; ++kx) {
          const int xc = xx + kx - 1;
          if (xc < 0 || xc >= H_) continue;
          conv += w9[ky * 3 + kx] * bfu2f(vb[((size_t)bh * NTOK + yy * H_ + xc) * HD_ + tid]);
        }
      }
      aob[((size_t)b * NTOK + t) * C_ + h * 64 + tid] = f2bfu(o + conv);
    }
    __syncthreads();
  }
}

// ---------------------------------------------------------------------------
// Proj GEMM: (B*320, 512) x (512,512) + bias -> d_out (f32), reading token i+2.
// ---------------------------------------------------------------------------
__global__ __launch_bounds__(256) void gemm_proj(
    const u16* __restrict__ A, const float* __restrict__ w,
    const float* __restrict__ bias, float* __restrict__ out)
{
  __shared__ float As[16][64];
  __shared__ float Bs[16][64];
  const int bn = blockIdx.x;   // 0..7
  const int bm = blockIdx.y;   // 0..639
  const int tid = threadIdx.x;
  const int tx = tid & 15, ty = tid >> 4;
  const int r = bm * 64 + (tid >> 2);
  const int b = r / N0_, ii = r - b * N0_;
  const u16* aptr = A + ((size_t)b * NTOK + ii + 2) * C_ + (tid & 3) * 4;
  const float* bptr = w + (size_t)(tid >> 4) * C_ + bn * 64 + ((tid & 15) * 4);
  float acc[4][4] = {};
  for (int k0 = 0; k0 < 512; k0 += 16) {
    const ushort4 ua = *(const ushort4*)(aptr + k0);
    const float4 gb4 = *(const float4*)(bptr + (size_t)k0 * C_);
    __syncthreads();
    As[(tid & 3) * 4 + 0][tid >> 2] = bfu2f(ua.x);
    As[(tid & 3) * 4 + 1][tid >> 2] = bfu2f(ua.y);
    As[(tid & 3) * 4 + 2][tid >> 2] = bfu2f(ua.z);
    As[(tid & 3) * 4 + 3][tid >> 2] = bfu2f(ua.w);
    *(float4*)&Bs[tid >> 4][(tid & 15) * 4] = gb4;
    __syncthreads();
    #pragma unroll
    for (int kk = 0; kk < 16; ++kk) {
      const float4 a4 = *(const float4*)&As[kk][ty * 4];
      const float4 b4 = *(const float4*)&Bs[kk][tx * 4];
      acc[0][0] += a4.x*b4.x; acc[0][1] += a4.x*b4.y; acc[0][2] += a4.x*b4.z; acc[0][3] += a4.x*b4.w;
      acc[1][0] += a4.y*b4.x; acc[1][1] += a4.y*b4.y; acc[1][2] += a4.y*b4.z; acc[1][3] += a4.y*b4.w;
      acc[2][0] += a4.z*b4.x; acc[2][1] += a4.z*b4.y; acc[2][2] += a4.z*b4.z; acc[2][3] += a4.z*b4.w;
      acc[3][0] += a4.w*b4.x; acc[3][1] += a4.w*b4.y; acc[3][2] += a4.w*b4.z; acc[3][3] += a4.w*b4.w;
    }
  }
  const int col = bn * 64 + tx * 4;
  const float4 pb = *(const float4*)&bias[col];
  #pragma unroll
  for (int i2 = 0; i2 < 4; ++i2) {
    const int rr = bm * 64 + ty * 4 + i2;
    const int bb = rr / N0_, iii = rr - bb * N0_;
    float4 o;
    o.x = acc[i2][0] + pb.x; o.y = acc[i2][1] + pb.y;
    o.z = acc[i2][2] + pb.z; o.w = acc[i2][3] + pb.w;
    *(float4*)&out[((size_t)bb * N0_ + iii) * C_ + col] = o;
  }
}

extern "C" void kernel_launch(void* const* d_in, const int* in_sizes, int n_in,
                              void* d_out, int out_size, void* d_ws, size_t ws_size,
                              hipStream_t stream)
{
  (void)in_sizes; (void)n_in; (void)out_size;
  const float* x      = (const float*)d_in[0];
  const float* qkv_w  = (const float*)d_in[1];
  const float* proj_w = (const float*)d_in[2];
  const float* proj_b = (const float*)d_in[3];
  const float* dwc_w  = (const float*)d_in[4];
  const float* dwc_b  = (const float*)d_in[5];
  const float* an     = (const float*)d_in[6];
  const float* na     = (const float*)d_in[7];
  const float* ah     = (const float*)d_in[8];
  const float* aw     = (const float*)d_in[9];
  const float* ha     = (const float*)d_in[10];
  const float* wa     = (const float*)d_in[11];

  char* ws = (char*)d_ws;
  const size_t QB  = (size_t)B_ * NH_ * NTOK * HD_ * 2;   // 42,467,328 B (bf16)
  const size_t AGB = (size_t)B_ * NH_ * AG_  * HD_ * 2;   // 18,874,368 B
  const size_t BB  = (size_t)NH_ * AG_ * NTOK * 4;        //  1,492,992 B
  u16* qb   = (u16*)(ws);
  u16* kb   = (u16*)(ws + QB);
  u16* vb   = (u16*)(ws + 2 * QB);
  u16* agb  = (u16*)(ws + 3 * QB);
  u16* avb  = (u16*)(ws + 3 * QB + AGB);
  float* bAN = (float*)(ws + 3 * QB + 2 * AGB);
  float* bNA = (float*)(ws + 3 * QB + 2 * AGB + BB);
  u16* aob  = kb;   // k is dead after stage1; reuse as attn_out
  if (ws_size < 3 * QB + 2 * AGB + 2 * BB) return;  // loud fail if ws too small

  bias_kernel<<<dim3(NH_ * AG_), dim3(324), 0, stream>>>(an, na, ah, aw, ha, wa, bAN, bNA);
  gemm_qkv  <<<dim3(24, 648),    dim3(256), 0, stream>>>(x, qkv_w, qb, kb, vb);
  pool_kernel<<<dim3(B_ * AG_),  dim3(512), 0, stream>>>(qb, agb);
  stage1_kernel<<<dim3(B_ * NH_), dim3(384), 0, stream>>>(kb, vb, agb, bAN, avb);
  stage2_kernel<<<dim3(B_, NH_, 4), dim3(256), 0, stream>>>(qb, agb, avb, vb, bNA, dwc_w, dwc_b, aob);
  gemm_proj <<<dim3(8, 640),     dim3(256), 0, stream>>>(aob, proj_w, proj_b, (float*)d_out);
}

// Round 3
// 1580.938 us; speedup vs baseline: 3.7931x; 3.7931x over previous
//
#include <hip/hip_runtime.h>

typedef unsigned short u16;
typedef short bf16x8 __attribute__((ext_vector_type(8)));
typedef float f32x4 __attribute__((ext_vector_type(4)));

#define B_    128
#define N0_   320
#define C_    512
#define NH_   8
#define HD_   64
#define NTOK  324
#define H_    18
#define AG_   144
#define SCALE 0.125f

__device__ __forceinline__ float bfu2f(u16 u) {
  union { unsigned int u; float f; } v; v.u = ((unsigned int)u) << 16; return v.f;
}
__device__ __forceinline__ u16 f2bfu(float f) {
  union { float f; unsigned int u; } v; v.f = f;
  unsigned int r = v.u + 0x7fffu + ((v.u >> 16) & 1u);
  return (u16)(r >> 16);
}

// ---------------------------------------------------------------------------
// Bias precompute (unchanged, verified round 2)
// ---------------------------------------------------------------------------
__global__ void bias_kernel(const float* __restrict__ an, const float* __restrict__ na,
                            const float* __restrict__ ah, const float* __restrict__ aw,
                            const float* __restrict__ ha, const float* __restrict__ wa,
                            float* __restrict__ bAN, float* __restrict__ bNA)
{
  const int blk = blockIdx.x;            // h*144 + a
  const int h = blk / AG_, a = blk - h * AG_;
  const int tid = threadIdx.x;
  if (tid >= NTOK) return;
  const int y = tid / H_, x = tid - y * H_;
  float cy = (y + 0.5f) * (7.0f / 18.0f) - 0.5f; cy = fminf(fmaxf(cy, 0.f), 6.f);
  float cx = (x + 0.5f) * (7.0f / 18.0f) - 0.5f; cx = fminf(fmaxf(cx, 0.f), 6.f);
  const int y0 = (int)floorf(cy); const float ty = cy - y0; const int y1 = min(y0 + 1, 6);
  const int x0 = (int)floorf(cx); const float tx = cx - x0; const int x1 = min(x0 + 1, 6);
  const float w00 = (1.f - ty) * (1.f - tx), w01 = (1.f - ty) * tx;
  const float w10 = ty * (1.f - tx), w11 = ty * tx;
  const float* anp = an + (size_t)blk * 49;
  const float* nap = na + (size_t)blk * 49;
  const float van = w00 * anp[y0*7+x0] + w01 * anp[y0*7+x1] + w10 * anp[y1*7+x0] + w11 * anp[y1*7+x1];
  const float vna = w00 * nap[y0*7+x0] + w01 * nap[y0*7+x1] + w10 * nap[y1*7+x0] + w11 * nap[y1*7+x1];
  bAN[(size_t)blk * NTOK + tid] = van + ah[(size_t)blk * H_ + y] + aw[(size_t)blk * H_ + x];
  bNA[((size_t)h * NTOK + tid) * AG_ + a] =
      vna + ha[((size_t)h * H_ + y) * AG_ + a] + wa[((size_t)h * H_ + x) * AG_ + a];
}

// ---------------------------------------------------------------------------
// QKV GEMM (unchanged, verified round 2)
// ---------------------------------------------------------------------------
__global__ __launch_bounds__(256) void gemm_qkv(
    const float* __restrict__ x, const float* __restrict__ w,
    u16* __restrict__ qb, u16* __restrict__ kb, u16* __restrict__ vb)
{
  __shared__ float As[16][64];
  __shared__ float Bs[16][64];
  const int bn = blockIdx.x;
  const int bm = blockIdx.y;
  const int tid = threadIdx.x;
  const int tx = tid & 15, ty = tid >> 4;

  const int arow = bm * 64 + (tid >> 2);
  const int ab = arow / NTOK;
  const int at = arow - ab * NTOK;
  const float* aptr = nullptr;
  if (at >= 2 && at < 322)
    aptr = x + ((size_t)(ab * N0_ + (at - 2))) * C_ + ((tid & 3) * 4);
  const float* bptr = w + (size_t)(tid >> 4) * 1536 + bn * 64 + ((tid & 15) * 4);

  float acc[4][4] = {};
  for (int k0 = 0; k0 < 512; k0 += 16) {
    float4 ga4 = make_float4(0.f, 0.f, 0.f, 0.f);
    if (aptr) ga4 = *(const float4*)(aptr + k0);
    const float4 gb4 = *(const float4*)(bptr + (size_t)k0 * 1536);
    __syncthreads();
    As[(tid & 3) * 4 + 0][tid >> 2] = ga4.x;
    As[(tid & 3) * 4 + 1][tid >> 2] = ga4.y;
    As[(tid & 3) * 4 + 2][tid >> 2] = ga4.z;
    As[(tid & 3) * 4 + 3][tid >> 2] = ga4.w;
    *(float4*)&Bs[tid >> 4][(tid & 15) * 4] = gb4;
    __syncthreads();
    #pragma unroll
    for (int kk = 0; kk < 16; ++kk) {
      const float4 a4 = *(const float4*)&As[kk][ty * 4];
      const float4 b4 = *(const float4*)&Bs[kk][tx * 4];
      acc[0][0] += a4.x*b4.x; acc[0][1] += a4.x*b4.y; acc[0][2] += a4.x*b4.z; acc[0][3] += a4.x*b4.w;
      acc[1][0] += a4.y*b4.x; acc[1][1] += a4.y*b4.y; acc[1][2] += a4.y*b4.z; acc[1][3] += a4.y*b4.w;
      acc[2][0] += a4.z*b4.x; acc[2][1] += a4.z*b4.y; acc[2][2] += a4.z*b4.z; acc[2][3] += a4.z*b4.w;
      acc[3][0] += a4.w*b4.x; acc[3][1] += a4.w*b4.y; acc[3][2] += a4.w*b4.z; acc[3][3] += a4.w*b4.w;
    }
  }
  const int mat = bn >> 3, h = bn & 7;
  u16* outp = (mat == 0) ? qb : (mat == 1) ? kb : vb;
  #pragma unroll
  for (int i = 0; i < 4; ++i) {
    const int r = bm * 64 + ty * 4 + i;
    const int b = r / NTOK, t = r - b * NTOK;
    ushort4 u;
    u.x = f2bfu(acc[i][0]); u.y = f2bfu(acc[i][1]); u.z = f2bfu(acc[i][2]); u.w = f2bfu(acc[i][3]);
    *(ushort4*)&outp[(((size_t)(b * NH_ + h)) * NTOK + t) * HD_ + tx * 4] = u;
  }
}

// ---------------------------------------------------------------------------
// Adaptive pool (unchanged, verified round 2)
// ---------------------------------------------------------------------------
__global__ __launch_bounds__(512) void pool_kernel(const u16* __restrict__ qb, u16* __restrict__ agb)
{
  const int blk = blockIdx.x;           // b*144 + a
  const int b = blk / AG_, a = blk - b * AG_;
  const int o = a / 12, pc = a - o * 12;
  const int y0 = (3 * o) >> 1, x0 = (3 * pc) >> 1;
  const int c = threadIdx.x; const int h = c >> 6, d = c & 63;
  const size_t base = ((size_t)(b * NH_ + h)) * NTOK * HD_ + d;
  const int t00 = (y0 * H_ + x0) * HD_;
  const float v = bfu2f(qb[base + t00]) + bfu2f(qb[base + t00 + HD_])
                + bfu2f(qb[base + t00 + H_ * HD_]) + bfu2f(qb[base + t00 + H_ * HD_ + HD_]);
  agb[((size_t)(b * NH_ + h)) * AG_ * HD_ + a * HD_ + d] = f2bfu(0.25f * v);
}

// ---------------------------------------------------------------------------
// Stage 1 (MFMA): S = ag @ K^T (M=144 agents, N=324->336 tokens, K=64)
//   col-softmax in D-frag regs -> P(bf16, LDS, K-pad 352) -> AV = P @ V (K=352)
// 9 waves = 9 agent m-tiles. A/B frags read from global (natural [row][k]).
// MFMA layouts: A row=l&15,k=(l>>4)*8+j; B col=l&15, same k; D col=l&15,row=(l>>4)*4+r.
// No block barrier after vT staging: each wave touches only its own pL rows.
// ---------------------------------------------------------------------------
__global__ __launch_bounds__(576) void stage1_mfma(
    const u16* __restrict__ kb, const u16* __restrict__ vb,
    const u16* __restrict__ agb, const float* __restrict__ bAN,
    u16* __restrict__ avb)
{
  __shared__ __align__(16) u16 vT[64 * 352];    // vT[d][token], tokens>=324 zero
  __shared__ __align__(16) u16 pL[144 * 352];   // P bf16 [agent][token-pad]
  const int bh = blockIdx.x;
  const int h  = bh & 7;
  const int tid = threadIdx.x;

  const u16* vsrc = vb + (size_t)bh * NTOK * HD_;
  for (int idx = tid; idx < 64 * 352; idx += 576) {
    const int d = idx & 63, n = idx >> 6;
    vT[d * 352 + n] = (n < NTOK) ? vsrc[n * HD_ + d] : (u16)0;
  }
  __syncthreads();

  const int mt = tid >> 6;        // wave = agent m-tile (0..8)
  const int l  = tid & 63;
  const int lr = l & 15;
  const int lk = l >> 4;

  // A-frags from agents (held across n-loop)
  const u16* aga = agb + ((size_t)bh * AG_ + mt * 16 + lr) * HD_ + lk * 8;
  const bf16x8 a0 = *(const bf16x8*)(aga);
  const bf16x8 a1 = *(const bf16x8*)(aga + 32);

  // QK: 21 token n-tiles (tile 20 partially valid)
  f32x4 acc[21];
  const u16* kbase = kb + (size_t)bh * NTOK * HD_ + lk * 8;
  #pragma unroll
  for (int nt = 0; nt < 21; ++nt) {
    const bf16x8 b0 = *(const bf16x8*)(kbase + (size_t)(nt * 16 + lr) * HD_);
    const bf16x8 b1 = *(const bf16x8*)(kbase + (size_t)(nt * 16 + lr) * HD_ + 32);
    f32x4 c = {0.f, 0.f, 0.f, 0.f};
    c = __builtin_amdgcn_mfma_f32_16x16x32_bf16(a0, b0, c, 0, 0, 0);
    c = __builtin_amdgcn_mfma_f32_16x16x32_bf16(a1, b1, c, 0, 0, 0);
    acc[nt] = c;
  }

  // scale + bias + masked col-softmax (reduce over the 16 lanes sharing lk)
  const float* bb = bAN + ((size_t)h * AG_ + mt * 16) * NTOK;
  float mx[4] = {-1e30f, -1e30f, -1e30f, -1e30f};
  #pragma unroll
  for (int nt = 0; nt < 21; ++nt) {
    const int col = nt * 16 + lr;
    const bool valid = (nt < 20) || (lr < 4);
    #pragma unroll
    for (int r = 0; r < 4; ++r) {
      float s = -1e30f;
      if (valid) s = acc[nt][r] * SCALE + bb[(lk * 4 + r) * NTOK + col];
      acc[nt][r] = s;
      mx[r] = fmaxf(mx[r], s);
    }
  }
  #pragma unroll
  for (int r = 0; r < 4; ++r) {
    #pragma unroll
    for (int o = 1; o < 16; o <<= 1) mx[r] = fmaxf(mx[r], __shfl_xor(mx[r], o));
  }
  float sm[4] = {0.f, 0.f, 0.f, 0.f};
  #pragma unroll
  for (int nt = 0; nt < 21; ++nt) {
    #pragma unroll
    for (int r = 0; r < 4; ++r) {
      const float e = __expf(acc[nt][r] - mx[r]);  // invalid cols underflow to 0
      acc[nt][r] = e;
      sm[r] += e;
    }
  }
  #pragma unroll
  for (int r = 0; r < 4; ++r) {
    #pragma unroll
    for (int o = 1; o < 16; o <<= 1) sm[r] += __shfl_xor(sm[r], o);
    sm[r] = 1.0f / sm[r];
  }
  #pragma unroll
  for (int nt = 0; nt < 21; ++nt) {
    #pragma unroll
    for (int r = 0; r < 4; ++r)
      pL[(mt * 16 + lk * 4 + r) * 352 + nt * 16 + lr] = f2bfu(acc[nt][r] * sm[r]);
  }
  #pragma unroll
  for (int r = 0; r < 4; ++r)                       // zero-pad tile (cols 336..351)
    pL[(mt * 16 + lk * 4 + r) * 352 + 336 + lr] = 0;

  // PV: AV = P @ V  (M=own 16 agents, N=64 d, K=352)
  f32x4 ov[4];
  #pragma unroll
  for (int nt2 = 0; nt2 < 4; ++nt2) ov[nt2] = (f32x4){0.f, 0.f, 0.f, 0.f};
  const u16* prow = &pL[(size_t)(mt * 16 + lr) * 352 + lk * 8];
  #pragma unroll
  for (int ks = 0; ks < 11; ++ks) {
    const bf16x8 pa = *(const bf16x8*)(prow + ks * 32);
    #pragma unroll
    for (int nt2 = 0; nt2 < 4; ++nt2) {
      const bf16x8 vf = *(const bf16x8*)(&vT[(size_t)(nt2 * 16 + lr) * 352 + ks * 32 + lk * 8]);
      ov[nt2] = __builtin_amdgcn_mfma_f32_16x16x32_bf16(pa, vf, ov[nt2], 0, 0, 0);
    }
  }
  #pragma unroll
  for (int nt2 = 0; nt2 < 4; ++nt2) {
    #pragma unroll
    for (int r = 0; r < 4; ++r)
      avb[((size_t)bh * AG_ + mt * 16 + lk * 4 + r) * HD_ + nt2 * 16 + lr] = f2bfu(ov[nt2][r]);
  }
}

// ---------------------------------------------------------------------------
// Stage 2 (MFMA) + fused dwc: S2 = q @ ag^T (M=324->336 tok, N=144 ag, K=64)
//   col-softmax -> P2(bf16, LDS, K-pad 160) -> out = P2 @ AV (K=160) + dwc(v)
// 8 waves; wave w owns m-tiles {w, w+8, w+16}.
// ---------------------------------------------------------------------------
__global__ __launch_bounds__(512) void stage2_mfma(
    const u16* __restrict__ qb, const u16* __restrict__ agb,
    const u16* __restrict__ avb, const u16* __restrict__ vb,
    const float* __restrict__ bNA, const float* __restrict__ dwc_w,
    const float* __restrict__ dwc_b, u16* __restrict__ aob)
{
  __shared__ __align__(16) u16 avT[64 * 160];   // avT[d][agent], agents>=144 zero
  __shared__ __align__(16) u16 pL2[336 * 160];  // P2 bf16 [token][agent-pad]
  const int bh = blockIdx.x; const int b = bh >> 3, h = bh & 7;
  const int tid = threadIdx.x;

  const u16* avsrc = avb + (size_t)bh * AG_ * HD_;
  for (int idx = tid; idx < 64 * 160; idx += 512) {
    const int d = idx & 63, a = idx >> 6;
    avT[d * 160 + a] = (a < AG_) ? avsrc[(size_t)a * HD_ + d] : (u16)0;
  }
  __syncthreads();

  const int wv = tid >> 6, l = tid & 63, lr = l & 15, lk = l >> 4;

  float w9[4][9]; float cb[4];
  #pragma unroll
  for (int nt2 = 0; nt2 < 4; ++nt2) {
    const int c = h * 64 + nt2 * 16 + lr;
    #pragma unroll
    for (int j = 0; j < 9; ++j) w9[nt2][j] = dwc_w[(size_t)c * 9 + j];
    cb[nt2] = dwc_b[c];
  }

  for (int mt = wv; mt < 21; mt += 8) {
    const int arow = min(mt * 16 + lr, NTOK - 1);       // clamp pad rows
    const u16* qa = qb + ((size_t)bh * NTOK + arow) * HD_ + lk * 8;
    const bf16x8 a0 = *(const bf16x8*)(qa);
    const bf16x8 a1 = *(const bf16x8*)(qa + 32);

    f32x4 acc[9];
    #pragma unroll
    for (int nt = 0; nt < 9; ++nt) {
      const u16* bp = agb + ((size_t)bh * AG_ + nt * 16 + lr) * HD_ + lk * 8;
      f32x4 c = {0.f, 0.f, 0.f, 0.f};
      c = __builtin_amdgcn_mfma_f32_16x16x32_bf16(a0, *(const bf16x8*)(bp), c, 0, 0, 0);
      c = __builtin_amdgcn_mfma_f32_16x16x32_bf16(a1, *(const bf16x8*)(bp + 32), c, 0, 0, 0);
      acc[nt] = c;
    }

    float mx[4] = {-1e30f, -1e30f, -1e30f, -1e30f};
    #pragma unroll
    for (int nt = 0; nt < 9; ++nt) {
      #pragma unroll
      for (int r = 0; r < 4; ++r) {
        const int trow = min(mt * 16 + lk * 4 + r, NTOK - 1);
        const float s = acc[nt][r] * SCALE + bNA[((size_t)h * NTOK + trow) * AG_ + nt * 16 + lr];
        acc[nt][r] = s;
        mx[r] = fmaxf(mx[r], s);
      }
    }
    #pragma unroll
    for (int r = 0; r < 4; ++r) {
      #pragma unroll
      for (int o = 1; o < 16; o <<= 1) mx[r] = fmaxf(mx[r], __shfl_xor(mx[r], o));
    }
    float sm[4] = {0.f, 0.f, 0.f, 0.f};
    #pragma unroll
    for (int nt = 0; nt < 9; ++nt) {
      #pragma unroll
      for (int r = 0; r < 4; ++r) {
        const float e = __expf(acc[nt][r] - mx[r]);
        acc[nt][r] = e;
        sm[r] += e;
      }
    }
    #pragma unroll
    for (int r = 0; r < 4; ++r) {
      #pragma unroll
      for (int o = 1; o < 16; o <<= 1) sm[r] += __shfl_xor(sm[r], o);
      sm[r] = 1.0f / sm[r];
    }
    #pragma unroll
    for (int nt = 0; nt < 9; ++nt) {
      #pragma unroll
      for (int r = 0; r < 4; ++r)
        pL2[(size_t)(mt * 16 + lk * 4 + r) * 160 + nt * 16 + lr] = f2bfu(acc[nt][r] * sm[r]);
    }
    #pragma unroll
    for (int r = 0; r < 4; ++r)                       // zero-pad tile (cols 144..159)
      pL2[(size_t)(mt * 16 + lk * 4 + r) * 160 + 144 + lr] = 0;

    f32x4 ov[4];
    #pragma unroll
    for (int nt2 = 0; nt2 < 4; ++nt2) ov[nt2] = (f32x4){0.f, 0.f, 0.f, 0.f};
    const u16* prow = &pL2[(size_t)(mt * 16 + lr) * 160 + lk * 8];
    #pragma unroll
    for (int ks = 0; ks < 5; ++ks) {
      const bf16x8 pa = *(const bf16x8*)(prow + ks * 32);
      #pragma unroll
      for (int nt2 = 0; nt2 < 4; ++nt2) {
        const bf16x8 vf = *(const bf16x8*)(&avT[(size_t)(nt2 * 16 + lr) * 160 + ks * 32 + lk * 8]);
        ov[nt2] = __builtin_amdgcn_mfma_f32_16x16x32_bf16(pa, vf, ov[nt2], 0, 0, 0);
      }
    }

    // epilogue: + depthwise conv, store aob[b][t][h*64+d]
    #pragma unroll
    for (int nt2 = 0; nt2 < 4; ++nt2) {
      #pragma unroll
      for (int r = 0; r < 4; ++r) {
        const int t = mt * 16 + lk * 4 + r;
        if (t < NTOK) {
          const int d = nt2 * 16 + lr;
          const int y = t / H_, x = t - y * H_;
          float conv = cb[nt2];
          #pragma unroll
          for (int ky = 0; ky < 3; ++ky) {
            const int yy = y + ky - 1;
            if (yy < 0 || yy >= H_) continue;
            #pragma unroll
            for (int kx = 0; kx < 3; ++kx) {
              const int xc = x + kx - 1;
              if (xc < 0 || xc >= H_) continue;
              conv += w9[nt2][ky * 3 + kx] * bfu2f(vb[((size_t)bh * NTOK + yy * H_ + xc) * HD_ + d]);
            }
          }
          aob[((size_t)b * NTOK + t) * C_ + h * 64 + d] = f2bfu(ov[nt2][r] + conv);
        }
      }
    }
  }
}

// ---------------------------------------------------------------------------
// Proj GEMM (unchanged, verified round 2)
// ---------------------------------------------------------------------------
__global__ __launch_bounds__(256) void gemm_proj(
    const u16* __restrict__ A, const float* __restrict__ w,
    const float* __restrict__ bias, float* __restrict__ out)
{
  __shared__ float As[16][64];
  __shared__ float Bs[16][64];
  const int bn = blockIdx.x;
  const int bm = blockIdx.y;
  const int tid = threadIdx.x;
  const int tx = tid & 15, ty = tid >> 4;
  const int r = bm * 64 + (tid >> 2);
  const int b = r / N0_, ii = r - b * N0_;
  const u16* aptr = A + ((size_t)b * NTOK + ii + 2) * C_ + (tid & 3) * 4;
  const float* bptr = w + (size_t)(tid >> 4) * C_ + bn * 64 + ((tid & 15) * 4);
  float acc[4][4] = {};
  for (int k0 = 0; k0 < 512; k0 += 16) {
    const ushort4 ua = *(const ushort4*)(aptr + k0);
    const float4 gb4 = *(const float4*)(bptr + (size_t)k0 * C_);
    __syncthreads();
    As[(tid & 3) * 4 + 0][tid >> 2] = bfu2f(ua.x);
    As[(tid & 3) * 4 + 1][tid >> 2] = bfu2f(ua.y);
    As[(tid & 3) * 4 + 2][tid >> 2] = bfu2f(ua.z);
    As[(tid & 3) * 4 + 3][tid >> 2] = bfu2f(ua.w);
    *(float4*)&Bs[tid >> 4][(tid & 15) * 4] = gb4;
    __syncthreads();
    #pragma unroll
    for (int kk = 0; kk < 16; ++kk) {
      const float4 a4 = *(const float4*)&As[kk][ty * 4];
      const float4 b4 = *(const float4*)&Bs[kk][tx * 4];
      acc[0][0] += a4.x*b4.x; acc[0][1] += a4.x*b4.y; acc[0][2] += a4.x*b4.z; acc[0][3] += a4.x*b4.w;
      acc[1][0] += a4.y*b4.x; acc[1][1] += a4.y*b4.y; acc[1][2] += a4.y*b4.z; acc[1][3] += a4.y*b4.w;
      acc[2][0] += a4.z*b4.x; acc[2][1] += a4.z*b4.y; acc[2][2] += a4.z*b4.z; acc[2][3] += a4.z*b4.w;
      acc[3][0] += a4.w*b4.x; acc[3][1] += a4.w*b4.y; acc[3][2] += a4.w*b4.z; acc[3][3] += a4.w*b4.w;
    }
  }
  const int col = bn * 64 + tx * 4;
  const float4 pb = *(const float4*)&bias[col];
  #pragma unroll
  for (int i2 = 0; i2 < 4; ++i2) {
    const int rr = bm * 64 + ty * 4 + i2;
    const int bb = rr / N0_, iii = rr - bb * N0_;
    float4 o;
    o.x = acc[i2][0] + pb.x; o.y = acc[i2][1] + pb.y;
    o.z = acc[i2][2] + pb.z; o.w = acc[i2][3] + pb.w;
    *(float4*)&out[((size_t)bb * N0_ + iii) * C_ + col] = o;
  }
}

extern "C" void kernel_launch(void* const* d_in, const int* in_sizes, int n_in,
                              void* d_out, int out_size, void* d_ws, size_t ws_size,
                              hipStream_t stream)
{
  (void)in_sizes; (void)n_in; (void)out_size;
  const float* x      = (const float*)d_in[0];
  const float* qkv_w  = (const float*)d_in[1];
  const float* proj_w = (const float*)d_in[2];
  const float* proj_b = (const float*)d_in[3];
  const float* dwc_w  = (const float*)d_in[4];
  const float* dwc_b  = (const float*)d_in[5];
  const float* an     = (const float*)d_in[6];
  const float* na     = (const float*)d_in[7];
  const float* ah     = (const float*)d_in[8];
  const float* aw     = (const float*)d_in[9];
  const float* ha     = (const float*)d_in[10];
  const float* wa     = (const float*)d_in[11];

  char* ws = (char*)d_ws;
  const size_t QB  = (size_t)B_ * NH_ * NTOK * HD_ * 2;   // 42,467,328 B (bf16)
  const size_t AGB = (size_t)B_ * NH_ * AG_  * HD_ * 2;   // 18,874,368 B
  const size_t BB  = (size_t)NH_ * AG_ * NTOK * 4;        //  1,492,992 B
  u16* qb   = (u16*)(ws);
  u16* kb   = (u16*)(ws + QB);
  u16* vb   = (u16*)(ws + 2 * QB);
  u16* agb  = (u16*)(ws + 3 * QB);
  u16* avb  = (u16*)(ws + 3 * QB + AGB);
  float* bAN = (float*)(ws + 3 * QB + 2 * AGB);
  float* bNA = (float*)(ws + 3 * QB + 2 * AGB + BB);
  u16* aob  = kb;   // k is dead after stage1; reuse as attn_out
  if (ws_size < 3 * QB + 2 * AGB + 2 * BB) return;

  bias_kernel<<<dim3(NH_ * AG_), dim3(324), 0, stream>>>(an, na, ah, aw, ha, wa, bAN, bNA);
  gemm_qkv  <<<dim3(24, 648),    dim3(256), 0, stream>>>(x, qkv_w, qb, kb, vb);
  pool_kernel<<<dim3(B_ * AG_),  dim3(512), 0, stream>>>(qb, agb);
  stage1_mfma<<<dim3(B_ * NH_),  dim3(576), 0, stream>>>(kb, vb, agb, bAN, avb);
  stage2_mfma<<<dim3(B_ * NH_),  dim3(512), 0, stream>>>(qb, agb, avb, vb, bNA, dwc_w, dwc_b, aob);
  gemm_proj <<<dim3(8, 640),     dim3(256), 0, stream>>>(aob, proj_w, proj_b, (float*)d_out);
}

// Round 4
// 637.510 us; speedup vs baseline: 9.4064x; 2.4799x over previous
//
#include <hip/hip_runtime.h>

typedef unsigned short u16;
typedef short bf16x8 __attribute__((ext_vector_type(8)));
typedef float f32x4 __attribute__((ext_vector_type(4)));

#define B_    128
#define N0_   320
#define C_    512
#define NH_   8
#define HD_   64
#define NTOK  324
#define H_    18
#define AG_   144
#define SCALE 0.125f

typedef __attribute__((address_space(3))) unsigned int as3_u32;
typedef __attribute__((address_space(1))) const unsigned int as1_u32;

__device__ __forceinline__ void gl_lds16(const void* g, void* l) {
  // 16B per lane, dest = wave-uniform LDS base + lane*16 (linear); src per-lane.
  __builtin_amdgcn_global_load_lds((as1_u32*)(unsigned long long)g,
                                   (as3_u32*)(unsigned int)(unsigned long long)l,
                                   16, 0, 0);
}

__device__ __forceinline__ float bfu2f(u16 u) {
  union { unsigned int u; float f; } v; v.u = ((unsigned int)u) << 16; return v.f;
}
__device__ __forceinline__ u16 f2bfu(float f) {
  union { float f; unsigned int u; } v; v.f = f;
  unsigned int r = v.u + 0x7fffu + ((v.u >> 16) & 1u);
  return (u16)(r >> 16);
}

// ---------------------------------------------------------------------------
// x (f32, [B][320][512]) -> xp (bf16, [B][324][512], pad tokens zero)
// ---------------------------------------------------------------------------
__global__ __launch_bounds__(256) void conv_x(const float* __restrict__ x, u16* __restrict__ xp)
{
  const int idx = blockIdx.x * 256 + threadIdx.x;      // one 8-elem chunk
  const int row = idx >> 6, c8 = idx & 63;
  const int b = row / NTOK, t = row - b * NTOK;
  u16 o[8];
  if (t < 2 || t >= 322) {
    #pragma unroll
    for (int j = 0; j < 8; ++j) o[j] = 0;
  } else {
    const float* src = x + ((size_t)(b * N0_ + (t - 2))) * C_ + c8 * 8;
    const float4 f0 = *(const float4*)(src);
    const float4 f1 = *(const float4*)(src + 4);
    o[0]=f2bfu(f0.x); o[1]=f2bfu(f0.y); o[2]=f2bfu(f0.z); o[3]=f2bfu(f0.w);
    o[4]=f2bfu(f1.x); o[5]=f2bfu(f1.y); o[6]=f2bfu(f1.z); o[7]=f2bfu(f1.w);
  }
  *(bf16x8*)&xp[(size_t)row * C_ + c8 * 8] = *(bf16x8*)o;
}

// ---------------------------------------------------------------------------
// W (f32, [512][ncols]) -> Wt (bf16, [ncols][512]) via LDS 64x64 tiles
// ---------------------------------------------------------------------------
__global__ __launch_bounds__(256) void tconv(const float* __restrict__ W, u16* __restrict__ Wt, int ncols)
{
  __shared__ float T[64][65];
  const int k0 = blockIdx.x * 64, n0 = blockIdx.y * 64;
  const int tid = threadIdx.x;
  const int rr = tid >> 4, cc = tid & 15;
  #pragma unroll
  for (int i = 0; i < 4; ++i) {
    const float4 f = *(const float4*)&W[(size_t)(k0 + i * 16 + rr) * ncols + n0 + cc * 4];
    T[i * 16 + rr][cc * 4 + 0] = f.x; T[i * 16 + rr][cc * 4 + 1] = f.y;
    T[i * 16 + rr][cc * 4 + 2] = f.z; T[i * 16 + rr][cc * 4 + 3] = f.w;
  }
  __syncthreads();
  #pragma unroll
  for (int i = 0; i < 4; ++i) {
    const int n = i * 16 + rr;
    ushort4 u;
    u.x = f2bfu(T[cc * 4 + 0][n]); u.y = f2bfu(T[cc * 4 + 1][n]);
    u.z = f2bfu(T[cc * 4 + 2][n]); u.w = f2bfu(T[cc * 4 + 3][n]);
    *(ushort4*)&Wt[(size_t)(n0 + n) * 512 + k0 + cc * 4] = u;
  }
}

// ---------------------------------------------------------------------------
// MFMA GEMM, 128x128 tile, BK=64, 256 thr (4 waves 2x2), global_load_lds w16,
// XOR-swizzled LDS (chunk c of row r at slot c^(r&7); inverse applied on the
// per-lane GLOBAL source so linear LDS dest ends up swizzled — rule #21).
// MODE 0: A=xp[41472][512], B=wqkvT[1536][512] -> q/k/v bf16 [bh][t][d]
// MODE 1: A=aob rows (b*324+ii+2), B=wprojT[512][512] -> d_out f32 + bias
// ---------------------------------------------------------------------------
template<int MODE>
__global__ __launch_bounds__(256) void mfma_gemm(
    const u16* __restrict__ A, const u16* __restrict__ Bt,
    u16* __restrict__ qb, u16* __restrict__ kb, u16* __restrict__ vb,
    const float* __restrict__ bias, float* __restrict__ outf)
{
  __shared__ __align__(16) u16 As[128 * 64];
  __shared__ __align__(16) u16 Bs[128 * 64];
  const int bx = blockIdx.x;            // N tile
  const int by = blockIdx.y;            // M tile
  const int tid = threadIdx.x;
  const int wv = tid >> 6, lane = tid & 63;
  const int lr = lane & 15, lk = lane >> 4;
  const int wr = wv >> 1, wc = wv & 1;
  const int si = lane >> 3, slot = lane & 7;

  // per-lane global row index for A staging (4 rows per wave-instr)
  size_t arow_src[4];
  #pragma unroll
  for (int jj = 0; jj < 4; ++jj) {
    const int rl = (wv * 4 + jj) * 8 + si;         // tile-local row 0..127
    const int r = by * 128 + rl;
    if (MODE == 0) {
      arow_src[jj] = (size_t)r;
    } else {
      const int b2 = r / N0_, ii = r - b2 * N0_;
      arow_src[jj] = (size_t)b2 * NTOK + ii + 2;
    }
  }

  f32x4 acc[4][4] = {};
  for (int k0 = 0; k0 < 512; k0 += 64) {
    __syncthreads();
    #pragma unroll
    for (int jj = 0; jj < 4; ++jj) {
      const int rl = (wv * 4 + jj) * 8 + si;
      const int c = slot ^ (rl & 7);
      gl_lds16(A + arow_src[jj] * 512 + k0 + c * 8,
               (char*)As + (wv * 4 + jj) * 1024);
      gl_lds16(Bt + (size_t)(bx * 128 + rl) * 512 + k0 + c * 8,
               (char*)Bs + (wv * 4 + jj) * 1024);
    }
    __syncthreads();   // compiler drains vmcnt before barrier
    #pragma unroll
    for (int kk = 0; kk < 2; ++kk) {
      bf16x8 af[4], bf[4];
      #pragma unroll
      for (int m = 0; m < 4; ++m) {
        const int row = wr * 64 + m * 16 + lr;
        af[m] = *(const bf16x8*)((const char*)As + row * 128 + (((kk * 4 + lk) ^ (row & 7)) << 4));
      }
      #pragma unroll
      for (int n = 0; n < 4; ++n) {
        const int row = wc * 64 + n * 16 + lr;
        bf[n] = *(const bf16x8*)((const char*)Bs + row * 128 + (((kk * 4 + lk) ^ (row & 7)) << 4));
      }
      #pragma unroll
      for (int m = 0; m < 4; ++m)
        #pragma unroll
        for (int n = 0; n < 4; ++n)
          acc[m][n] = __builtin_amdgcn_mfma_f32_16x16x32_bf16(af[m], bf[n], acc[m][n], 0, 0, 0);
    }
  }

  if (MODE == 0) {
    const int mat = (bx * 128) >> 9;
    u16* outp = (mat == 0) ? qb : (mat == 1) ? kb : vb;
    #pragma unroll
    for (int m = 0; m < 4; ++m) {
      #pragma unroll
      for (int r = 0; r < 4; ++r) {
        const int row = by * 128 + wr * 64 + m * 16 + lk * 4 + r;
        const int b = row / NTOK, t = row - b * NTOK;
        #pragma unroll
        for (int n = 0; n < 4; ++n) {
          const int col = bx * 128 + wc * 64 + n * 16 + lr;
          const int rem = col & 511, h = rem >> 6, d = rem & 63;
          outp[(((size_t)(b * NH_ + h)) * NTOK + t) * HD_ + d] = f2bfu(acc[m][n][r]);
        }
      }
    }
  } else {
    #pragma unroll
    for (int m = 0; m < 4; ++m) {
      #pragma unroll
      for (int r = 0; r < 4; ++r) {
        const int row = by * 128 + wr * 64 + m * 16 + lk * 4 + r;
        #pragma unroll
        for (int n = 0; n < 4; ++n) {
          const int col = bx * 128 + wc * 64 + n * 16 + lr;
          outf[(size_t)row * C_ + col] = acc[m][n][r] + bias[col];
        }
      }
    }
  }
}

// ---------------------------------------------------------------------------
// Bias precompute (unchanged, verified)
// ---------------------------------------------------------------------------
__global__ void bias_kernel(const float* __restrict__ an, const float* __restrict__ na,
                            const float* __restrict__ ah, const float* __restrict__ aw,
                            const float* __restrict__ ha, const float* __restrict__ wa,
                            float* __restrict__ bAN, float* __restrict__ bNA)
{
  const int blk = blockIdx.x;            // h*144 + a
  const int h = blk / AG_, a = blk - h * AG_;
  const int tid = threadIdx.x;
  if (tid >= NTOK) return;
  const int y = tid / H_, x = tid - y * H_;
  float cy = (y + 0.5f) * (7.0f / 18.0f) - 0.5f; cy = fminf(fmaxf(cy, 0.f), 6.f);
  float cx = (x + 0.5f) * (7.0f / 18.0f) - 0.5f; cx = fminf(fmaxf(cx, 0.f), 6.f);
  const int y0 = (int)floorf(cy); const float ty = cy - y0; const int y1 = min(y0 + 1, 6);
  const int x0 = (int)floorf(cx); const float tx = cx - x0; const int x1 = min(x0 + 1, 6);
  const float w00 = (1.f - ty) * (1.f - tx), w01 = (1.f - ty) * tx;
  const float w10 = ty * (1.f - tx), w11 = ty * tx;
  const float* anp = an + (size_t)blk * 49;
  const float* nap = na + (size_t)blk * 49;
  const float van = w00 * anp[y0*7+x0] + w01 * anp[y0*7+x1] + w10 * anp[y1*7+x0] + w11 * anp[y1*7+x1];
  const float vna = w00 * nap[y0*7+x0] + w01 * nap[y0*7+x1] + w10 * nap[y1*7+x0] + w11 * nap[y1*7+x1];
  bAN[(size_t)blk * NTOK + tid] = van + ah[(size_t)blk * H_ + y] + aw[(size_t)blk * H_ + x];
  bNA[((size_t)h * NTOK + tid) * AG_ + a] =
      vna + ha[((size_t)h * H_ + y) * AG_ + a] + wa[((size_t)h * H_ + x) * AG_ + a];
}

// ---------------------------------------------------------------------------
// Adaptive pool (unchanged, verified)
// ---------------------------------------------------------------------------
__global__ __launch_bounds__(512) void pool_kernel(const u16* __restrict__ qb, u16* __restrict__ agb)
{
  const int blk = blockIdx.x;           // b*144 + a
  const int b = blk / AG_, a = blk - b * AG_;
  const int o = a / 12, pc = a - o * 12;
  const int y0 = (3 * o) >> 1, x0 = (3 * pc) >> 1;
  const int c = threadIdx.x; const int h = c >> 6, d = c & 63;
  const size_t base = ((size_t)(b * NH_ + h)) * NTOK * HD_ + d;
  const int t00 = (y0 * H_ + x0) * HD_;
  const float v = bfu2f(qb[base + t00]) + bfu2f(qb[base + t00 + HD_])
                + bfu2f(qb[base + t00 + H_ * HD_]) + bfu2f(qb[base + t00 + H_ * HD_ + HD_]);
  agb[((size_t)(b * NH_ + h)) * AG_ * HD_ + a * HD_ + d] = f2bfu(0.25f * v);
}

// ---------------------------------------------------------------------------
// Stage 1 (MFMA, unchanged, verified round 3)
// ---------------------------------------------------------------------------
__global__ __launch_bounds__(576) void stage1_mfma(
    const u16* __restrict__ kb, const u16* __restrict__ vb,
    const u16* __restrict__ agb, const float* __restrict__ bAN,
    u16* __restrict__ avb)
{
  __shared__ __align__(16) u16 vT[64 * 352];    // vT[d][token], tokens>=324 zero
  __shared__ __align__(16) u16 pL[144 * 352];   // P bf16 [agent][token-pad]
  const int bh = blockIdx.x;
  const int h  = bh & 7;
  const int tid = threadIdx.x;

  const u16* vsrc = vb + (size_t)bh * NTOK * HD_;
  for (int idx = tid; idx < 64 * 352; idx += 576) {
    const int d = idx & 63, n = idx >> 6;
    vT[d * 352 + n] = (n < NTOK) ? vsrc[n * HD_ + d] : (u16)0;
  }
  __syncthreads();

  const int mt = tid >> 6;        // wave = agent m-tile (0..8)
  const int l  = tid & 63;
  const int lr = l & 15;
  const int lk = l >> 4;

  const u16* aga = agb + ((size_t)bh * AG_ + mt * 16 + lr) * HD_ + lk * 8;
  const bf16x8 a0 = *(const bf16x8*)(aga);
  const bf16x8 a1 = *(const bf16x8*)(aga + 32);

  f32x4 acc[21];
  const u16* kbase = kb + (size_t)bh * NTOK * HD_ + lk * 8;
  #pragma unroll
  for (int nt = 0; nt < 21; ++nt) {
    const bf16x8 b0 = *(const bf16x8*)(kbase + (size_t)(nt * 16 + lr) * HD_);
    const bf16x8 b1 = *(const bf16x8*)(kbase + (size_t)(nt * 16 + lr) * HD_ + 32);
    f32x4 c = {0.f, 0.f, 0.f, 0.f};
    c = __builtin_amdgcn_mfma_f32_16x16x32_bf16(a0, b0, c, 0, 0, 0);
    c = __builtin_amdgcn_mfma_f32_16x16x32_bf16(a1, b1, c, 0, 0, 0);
    acc[nt] = c;
  }

  const float* bb = bAN + ((size_t)h * AG_ + mt * 16) * NTOK;
  float mx[4] = {-1e30f, -1e30f, -1e30f, -1e30f};
  #pragma unroll
  for (int nt = 0; nt < 21; ++nt) {
    const int col = nt * 16 + lr;
    const bool valid = (nt < 20) || (lr < 4);
    #pragma unroll
    for (int r = 0; r < 4; ++r) {
      float s = -1e30f;
      if (valid) s = acc[nt][r] * SCALE + bb[(lk * 4 + r) * NTOK + col];
      acc[nt][r] = s;
      mx[r] = fmaxf(mx[r], s);
    }
  }
  #pragma unroll
  for (int r = 0; r < 4; ++r) {
    #pragma unroll
    for (int o = 1; o < 16; o <<= 1) mx[r] = fmaxf(mx[r], __shfl_xor(mx[r], o));
  }
  float sm[4] = {0.f, 0.f, 0.f, 0.f};
  #pragma unroll
  for (int nt = 0; nt < 21; ++nt) {
    #pragma unroll
    for (int r = 0; r < 4; ++r) {
      const float e = __expf(acc[nt][r] - mx[r]);
      acc[nt][r] = e;
      sm[r] += e;
    }
  }
  #pragma unroll
  for (int r = 0; r < 4; ++r) {
    #pragma unroll
    for (int o = 1; o < 16; o <<= 1) sm[r] += __shfl_xor(sm[r], o);
    sm[r] = 1.0f / sm[r];
  }
  #pragma unroll
  for (int nt = 0; nt < 21; ++nt) {
    #pragma unroll
    for (int r = 0; r < 4; ++r)
      pL[(mt * 16 + lk * 4 + r) * 352 + nt * 16 + lr] = f2bfu(acc[nt][r] * sm[r]);
  }
  #pragma unroll
  for (int r = 0; r < 4; ++r)
    pL[(mt * 16 + lk * 4 + r) * 352 + 336 + lr] = 0;

  f32x4 ov[4];
  #pragma unroll
  for (int nt2 = 0; nt2 < 4; ++nt2) ov[nt2] = (f32x4){0.f, 0.f, 0.f, 0.f};
  const u16* prow = &pL[(size_t)(mt * 16 + lr) * 352 + lk * 8];
  #pragma unroll
  for (int ks = 0; ks < 11; ++ks) {
    const bf16x8 pa = *(const bf16x8*)(prow + ks * 32);
    #pragma unroll
    for (int nt2 = 0; nt2 < 4; ++nt2) {
      const bf16x8 vf = *(const bf16x8*)(&vT[(size_t)(nt2 * 16 + lr) * 352 + ks * 32 + lk * 8]);
      ov[nt2] = __builtin_amdgcn_mfma_f32_16x16x32_bf16(pa, vf, ov[nt2], 0, 0, 0);
    }
  }
  #pragma unroll
  for (int nt2 = 0; nt2 < 4; ++nt2) {
    #pragma unroll
    for (int r = 0; r < 4; ++r)
      avb[((size_t)bh * AG_ + mt * 16 + lk * 4 + r) * HD_ + nt2 * 16 + lr] = f2bfu(ov[nt2][r]);
  }
}

// ---------------------------------------------------------------------------
// Stage 2 (MFMA) + fused dwc (unchanged, verified round 3)
// ---------------------------------------------------------------------------
__global__ __launch_bounds__(512) void stage2_mfma(
    const u16* __restrict__ qb, const u16* __restrict__ agb,
    const u16* __restrict__ avb, const u16* __restrict__ vb,
    const float* __restrict__ bNA, const float* __restrict__ dwc_w,
    const float* __restrict__ dwc_b, u16* __restrict__ aob)
{
  __shared__ __align__(16) u16 avT[64 * 160];
  __shared__ __align__(16) u16 pL2[336 * 160];
  const int bh = blockIdx.x; const int b = bh >> 3, h = bh & 7;
  const int tid = threadIdx.x;

  const u16* avsrc = avb + (size_t)bh * AG_ * HD_;
  for (int idx = tid; idx < 64 * 160; idx += 512) {
    const int d = idx & 63, a = idx >> 6;
    avT[d * 160 + a] = (a < AG_) ? avsrc[(size_t)a * HD_ + d] : (u16)0;
  }
  __syncthreads();

  const int wv = tid >> 6, l = tid & 63, lr = l & 15, lk = l >> 4;

  float w9[4][9]; float cb[4];
  #pragma unroll
  for (int nt2 = 0; nt2 < 4; ++nt2) {
    const int c = h * 64 + nt2 * 16 + lr;
    #pragma unroll
    for (int j = 0; j < 9; ++j) w9[nt2][j] = dwc_w[(size_t)c * 9 + j];
    cb[nt2] = dwc_b[c];
  }

  for (int mt = wv; mt < 21; mt += 8) {
    const int arow = min(mt * 16 + lr, NTOK - 1);
    const u16* qa = qb + ((size_t)bh * NTOK + arow) * HD_ + lk * 8;
    const bf16x8 a0 = *(const bf16x8*)(qa);
    const bf16x8 a1 = *(const bf16x8*)(qa + 32);

    f32x4 acc[9];
    #pragma unroll
    for (int nt = 0; nt < 9; ++nt) {
      const u16* bp = agb + ((size_t)bh * AG_ + nt * 16 + lr) * HD_ + lk * 8;
      f32x4 c = {0.f, 0.f, 0.f, 0.f};
      c = __builtin_amdgcn_mfma_f32_16x16x32_bf16(a0, *(const bf16x8*)(bp), c, 0, 0, 0);
      c = __builtin_amdgcn_mfma_f32_16x16x32_bf16(a1, *(const bf16x8*)(bp + 32), c, 0, 0, 0);
      acc[nt] = c;
    }

    float mx[4] = {-1e30f, -1e30f, -1e30f, -1e30f};
    #pragma unroll
    for (int nt = 0; nt < 9; ++nt) {
      #pragma unroll
      for (int r = 0; r < 4; ++r) {
        const int trow = min(mt * 16 + lk * 4 + r, NTOK - 1);
        const float s = acc[nt][r] * SCALE + bNA[((size_t)h * NTOK + trow) * AG_ + nt * 16 + lr];
        acc[nt][r] = s;
        mx[r] = fmaxf(mx[r], s);
      }
    }
    #pragma unroll
    for (int r = 0; r < 4; ++r) {
      #pragma unroll
      for (int o = 1; o < 16; o <<= 1) mx[r] = fmaxf(mx[r], __shfl_xor(mx[r], o));
    }
    float sm[4] = {0.f, 0.f, 0.f, 0.f};
    #pragma unroll
    for (int nt = 0; nt < 9; ++nt) {
      #pragma unroll
      for (int r = 0; r < 4; ++r) {
        const float e = __expf(acc[nt][r] - mx[r]);
        acc[nt][r] = e;
        sm[r] += e;
      }
    }
    #pragma unroll
    for (int r = 0; r < 4; ++r) {
      #pragma unroll
      for (int o = 1; o < 16; o <<= 1) sm[r] += __shfl_xor(sm[r], o);
      sm[r] = 1.0f / sm[r];
    }
    #pragma unroll
    for (int nt = 0; nt < 9; ++nt) {
      #pragma unroll
      for (int r = 0; r < 4; ++r)
        pL2[(size_t)(mt * 16 + lk * 4 + r) * 160 + nt * 16 + lr] = f2bfu(acc[nt][r] * sm[r]);
    }
    #pragma unroll
    for (int r = 0; r < 4; ++r)
      pL2[(size_t)(mt * 16 + lk * 4 + r) * 160 + 144 + lr] = 0;

    f32x4 ov[4];
    #pragma unroll
    for (int nt2 = 0; nt2 < 4; ++nt2) ov[nt2] = (f32x4){0.f, 0.f, 0.f, 0.f};
    const u16* prow = &pL2[(size_t)(mt * 16 + lr) * 160 + lk * 8];
    #pragma unroll
    for (int ks = 0; ks < 5; ++ks) {
      const bf16x8 pa = *(const bf16x8*)(prow + ks * 32);
      #pragma unroll
      for (int nt2 = 0; nt2 < 4; ++nt2) {
        const bf16x8 vf = *(const bf16x8*)(&avT[(size_t)(nt2 * 16 + lr) * 160 + ks * 32 + lk * 8]);
        ov[nt2] = __builtin_amdgcn_mfma_f32_16x16x32_bf16(pa, vf, ov[nt2], 0, 0, 0);
      }
    }

    #pragma unroll
    for (int nt2 = 0; nt2 < 4; ++nt2) {
      #pragma unroll
      for (int r = 0; r < 4; ++r) {
        const int t = mt * 16 + lk * 4 + r;
        if (t < NTOK) {
          const int d = nt2 * 16 + lr;
          const int y = t / H_, x = t - y * H_;
          float conv = cb[nt2];
          #pragma unroll
          for (int ky = 0; ky < 3; ++ky) {
            const int yy = y + ky - 1;
            if (yy < 0 || yy >= H_) continue;
            #pragma unroll
            for (int kx = 0; kx < 3; ++kx) {
              const int xc = x + kx - 1;
              if (xc < 0 || xc >= H_) continue;
              conv += w9[nt2][ky * 3 + kx] * bfu2f(vb[((size_t)bh * NTOK + yy * H_ + xc) * HD_ + d]);
            }
          }
          aob[((size_t)b * NTOK + t) * C_ + h * 64 + d] = f2bfu(ov[nt2][r] + conv);
        }
      }
    }
  }
}

extern "C" void kernel_launch(void* const* d_in, const int* in_sizes, int n_in,
                              void* d_out, int out_size, void* d_ws, size_t ws_size,
                              hipStream_t stream)
{
  (void)in_sizes; (void)n_in; (void)out_size;
  const float* x      = (const float*)d_in[0];
  const float* qkv_w  = (const float*)d_in[1];
  const float* proj_w = (const float*)d_in[2];
  const float* proj_b = (const float*)d_in[3];
  const float* dwc_w  = (const float*)d_in[4];
  const float* dwc_b  = (const float*)d_in[5];
  const float* an     = (const float*)d_in[6];
  const float* na     = (const float*)d_in[7];
  const float* ah     = (const float*)d_in[8];
  const float* aw     = (const float*)d_in[9];
  const float* ha     = (const float*)d_in[10];
  const float* wa     = (const float*)d_in[11];

  char* ws = (char*)d_ws;
  const size_t QB  = (size_t)B_ * NH_ * NTOK * HD_ * 2;   // 42,467,328 (== xp bytes)
  const size_t AGB = (size_t)B_ * NH_ * AG_  * HD_ * 2;   // 18,874,368
  const size_t BB  = (size_t)NH_ * AG_ * NTOK * 4;        //  1,492,992
  u16* qb   = (u16*)(ws);
  u16* kb   = (u16*)(ws + QB);
  u16* vb   = (u16*)(ws + 2 * QB);
  u16* xp   = (u16*)(ws + 3 * QB);                        // dead after qkv GEMM
  u16* agb  = (u16*)(ws + 3 * QB);                        // overlays xp (after)
  u16* avb  = (u16*)(ws + 3 * QB + AGB);
  float* bAN = (float*)(ws + 3 * QB + 2 * AGB);
  float* bNA = (float*)(ws + 3 * QB + 2 * AGB + BB);      // ends 40.7MB into xp's 42.5MB
  u16* wqkvT = (u16*)(ws + 4 * QB);                       // 1.57 MB
  u16* wprojT = (u16*)(ws + 4 * QB + (size_t)1536 * 512 * 2);  // 0.52 MB
  u16* aob  = kb;                                         // k dead after stage1
  if (ws_size < 4 * QB + (size_t)1536 * 512 * 2 + (size_t)512 * 512 * 2) return;

  conv_x   <<<dim3(B_ * NTOK * 64 / 256), dim3(256), 0, stream>>>(x, xp);
  tconv    <<<dim3(8, 24), dim3(256), 0, stream>>>(qkv_w, wqkvT, 1536);
  tconv    <<<dim3(8, 8),  dim3(256), 0, stream>>>(proj_w, wprojT, 512);
  mfma_gemm<0><<<dim3(12, 324), dim3(256), 0, stream>>>(xp, wqkvT, qb, kb, vb, nullptr, nullptr);
  pool_kernel<<<dim3(B_ * AG_),  dim3(512), 0, stream>>>(qb, agb);      // overlays xp
  bias_kernel<<<dim3(NH_ * AG_), dim3(324), 0, stream>>>(an, na, ah, aw, ha, wa, bAN, bNA);
  stage1_mfma<<<dim3(B_ * NH_),  dim3(576), 0, stream>>>(kb, vb, agb, bAN, avb);
  stage2_mfma<<<dim3(B_ * NH_),  dim3(512), 0, stream>>>(qb, agb, avb, vb, bNA, dwc_w, dwc_b, aob);
  mfma_gemm<1><<<dim3(4, 320), dim3(256), 0, stream>>>(aob, wprojT, nullptr, nullptr, nullptr, proj_b, (float*)d_out);
}

// Round 5
// 482.640 us; speedup vs baseline: 12.4248x; 1.3209x over previous
//
#include <hip/hip_runtime.h>

typedef unsigned short u16;
typedef short bf16x8 __attribute__((ext_vector_type(8)));
typedef float f32x4 __attribute__((ext_vector_type(4)));

#define B_    128
#define N0_   320
#define C_    512
#define NH_   8
#define HD_   64
#define NTOK  324
#define H_    18
#define AG_   144
#define SCALE 0.125f

typedef __attribute__((address_space(3))) unsigned int as3_u32;
typedef __attribute__((address_space(1))) const unsigned int as1_u32;

__device__ __forceinline__ void gl_lds16(const void* g, void* l) {
  __builtin_amdgcn_global_load_lds((as1_u32*)(unsigned long long)g,
                                   (as3_u32*)(unsigned int)(unsigned long long)l,
                                   16, 0, 0);
}

__device__ __forceinline__ float bfu2f(u16 u) {
  union { unsigned int u; float f; } v; v.u = ((unsigned int)u) << 16; return v.f;
}
__device__ __forceinline__ u16 f2bfu(float f) {
  union { float f; unsigned int u; } v; v.f = f;
  unsigned int r = v.u + 0x7fffu + ((v.u >> 16) & 1u);
  return (u16)(r >> 16);
}

// ---------------------------------------------------------------------------
// x (f32) -> xp (bf16, [B][324][512], pad tokens zero)
// ---------------------------------------------------------------------------
__global__ __launch_bounds__(256) void conv_x(const float* __restrict__ x, u16* __restrict__ xp)
{
  const int idx = blockIdx.x * 256 + threadIdx.x;
  const int row = idx >> 6, c8 = idx & 63;
  const int b = row / NTOK, t = row - b * NTOK;
  u16 o[8];
  if (t < 2 || t >= 322) {
    #pragma unroll
    for (int j = 0; j < 8; ++j) o[j] = 0;
  } else {
    const float* src = x + ((size_t)(b * N0_ + (t - 2))) * C_ + c8 * 8;
    const float4 f0 = *(const float4*)(src);
    const float4 f1 = *(const float4*)(src + 4);
    o[0]=f2bfu(f0.x); o[1]=f2bfu(f0.y); o[2]=f2bfu(f0.z); o[3]=f2bfu(f0.w);
    o[4]=f2bfu(f1.x); o[5]=f2bfu(f1.y); o[6]=f2bfu(f1.z); o[7]=f2bfu(f1.w);
  }
  *(bf16x8*)&xp[(size_t)row * C_ + c8 * 8] = *(bf16x8*)o;
}

// ---------------------------------------------------------------------------
// W (f32, [512][ncols]) -> Wt (bf16, [ncols][512])
// ---------------------------------------------------------------------------
__global__ __launch_bounds__(256) void tconv(const float* __restrict__ W, u16* __restrict__ Wt, int ncols)
{
  __shared__ float T[64][65];
  const int k0 = blockIdx.x * 64, n0 = blockIdx.y * 64;
  const int tid = threadIdx.x;
  const int rr = tid >> 4, cc = tid & 15;
  #pragma unroll
  for (int i = 0; i < 4; ++i) {
    const float4 f = *(const float4*)&W[(size_t)(k0 + i * 16 + rr) * ncols + n0 + cc * 4];
    T[i * 16 + rr][cc * 4 + 0] = f.x; T[i * 16 + rr][cc * 4 + 1] = f.y;
    T[i * 16 + rr][cc * 4 + 2] = f.z; T[i * 16 + rr][cc * 4 + 3] = f.w;
  }
  __syncthreads();
  #pragma unroll
  for (int i = 0; i < 4; ++i) {
    const int n = i * 16 + rr;
    ushort4 u;
    u.x = f2bfu(T[cc * 4 + 0][n]); u.y = f2bfu(T[cc * 4 + 1][n]);
    u.z = f2bfu(T[cc * 4 + 2][n]); u.w = f2bfu(T[cc * 4 + 3][n]);
    *(ushort4*)&Wt[(size_t)(n0 + n) * 512 + k0 + cc * 4] = u;
  }
}

// ---------------------------------------------------------------------------
// MFMA GEMM (unchanged, verified round 4)
// ---------------------------------------------------------------------------
template<int MODE>
__global__ __launch_bounds__(256) void mfma_gemm(
    const u16* __restrict__ A, const u16* __restrict__ Bt,
    u16* __restrict__ qb, u16* __restrict__ kb, u16* __restrict__ vb,
    const float* __restrict__ bias, float* __restrict__ outf)
{
  __shared__ __align__(16) u16 As[128 * 64];
  __shared__ __align__(16) u16 Bs[128 * 64];
  const int bx = blockIdx.x;
  const int by = blockIdx.y;
  const int tid = threadIdx.x;
  const int wv = tid >> 6, lane = tid & 63;
  const int lr = lane & 15, lk = lane >> 4;
  const int wr = wv >> 1, wc = wv & 1;
  const int si = lane >> 3, slot = lane & 7;

  size_t arow_src[4];
  #pragma unroll
  for (int jj = 0; jj < 4; ++jj) {
    const int rl = (wv * 4 + jj) * 8 + si;
    const int r = by * 128 + rl;
    if (MODE == 0) {
      arow_src[jj] = (size_t)r;
    } else {
      const int b2 = r / N0_, ii = r - b2 * N0_;
      arow_src[jj] = (size_t)b2 * NTOK + ii + 2;
    }
  }

  f32x4 acc[4][4] = {};
  for (int k0 = 0; k0 < 512; k0 += 64) {
    __syncthreads();
    #pragma unroll
    for (int jj = 0; jj < 4; ++jj) {
      const int rl = (wv * 4 + jj) * 8 + si;
      const int c = slot ^ (rl & 7);
      gl_lds16(A + arow_src[jj] * 512 + k0 + c * 8,
               (char*)As + (wv * 4 + jj) * 1024);
      gl_lds16(Bt + (size_t)(bx * 128 + rl) * 512 + k0 + c * 8,
               (char*)Bs + (wv * 4 + jj) * 1024);
    }
    __syncthreads();
    #pragma unroll
    for (int kk = 0; kk < 2; ++kk) {
      bf16x8 af[4], bf[4];
      #pragma unroll
      for (int m = 0; m < 4; ++m) {
        const int row = wr * 64 + m * 16 + lr;
        af[m] = *(const bf16x8*)((const char*)As + row * 128 + (((kk * 4 + lk) ^ (row & 7)) << 4));
      }
      #pragma unroll
      for (int n = 0; n < 4; ++n) {
        const int row = wc * 64 + n * 16 + lr;
        bf[n] = *(const bf16x8*)((const char*)Bs + row * 128 + (((kk * 4 + lk) ^ (row & 7)) << 4));
      }
      #pragma unroll
      for (int m = 0; m < 4; ++m)
        #pragma unroll
        for (int n = 0; n < 4; ++n)
          acc[m][n] = __builtin_amdgcn_mfma_f32_16x16x32_bf16(af[m], bf[n], acc[m][n], 0, 0, 0);
    }
  }

  if (MODE == 0) {
    const int mat = (bx * 128) >> 9;
    u16* outp = (mat == 0) ? qb : (mat == 1) ? kb : vb;
    #pragma unroll
    for (int m = 0; m < 4; ++m) {
      #pragma unroll
      for (int r = 0; r < 4; ++r) {
        const int row = by * 128 + wr * 64 + m * 16 + lk * 4 + r;
        const int b = row / NTOK, t = row - b * NTOK;
        #pragma unroll
        for (int n = 0; n < 4; ++n) {
          const int col = bx * 128 + wc * 64 + n * 16 + lr;
          const int rem = col & 511, h = rem >> 6, d = rem & 63;
          outp[(((size_t)(b * NH_ + h)) * NTOK + t) * HD_ + d] = f2bfu(acc[m][n][r]);
        }
      }
    }
  } else {
    #pragma unroll
    for (int m = 0; m < 4; ++m) {
      #pragma unroll
      for (int r = 0; r < 4; ++r) {
        const int row = by * 128 + wr * 64 + m * 16 + lk * 4 + r;
        #pragma unroll
        for (int n = 0; n < 4; ++n) {
          const int col = bx * 128 + wc * 64 + n * 16 + lr;
          outf[(size_t)row * C_ + col] = acc[m][n][r] + bias[col];
        }
      }
    }
  }
}

// ---------------------------------------------------------------------------
// Bias precompute (unchanged, verified)
// ---------------------------------------------------------------------------
__global__ void bias_kernel(const float* __restrict__ an, const float* __restrict__ na,
                            const float* __restrict__ ah, const float* __restrict__ aw,
                            const float* __restrict__ ha, const float* __restrict__ wa,
                            float* __restrict__ bAN, float* __restrict__ bNA)
{
  const int blk = blockIdx.x;
  const int h = blk / AG_, a = blk - h * AG_;
  const int tid = threadIdx.x;
  if (tid >= NTOK) return;
  const int y = tid / H_, x = tid - y * H_;
  float cy = (y + 0.5f) * (7.0f / 18.0f) - 0.5f; cy = fminf(fmaxf(cy, 0.f), 6.f);
  float cx = (x + 0.5f) * (7.0f / 18.0f) - 0.5f; cx = fminf(fmaxf(cx, 0.f), 6.f);
  const int y0 = (int)floorf(cy); const float ty = cy - y0; const int y1 = min(y0 + 1, 6);
  const int x0 = (int)floorf(cx); const float tx = cx - x0; const int x1 = min(x0 + 1, 6);
  const float w00 = (1.f - ty) * (1.f - tx), w01 = (1.f - ty) * tx;
  const float w10 = ty * (1.f - tx), w11 = ty * tx;
  const float* anp = an + (size_t)blk * 49;
  const float* nap = na + (size_t)blk * 49;
  const float van = w00 * anp[y0*7+x0] + w01 * anp[y0*7+x1] + w10 * anp[y1*7+x0] + w11 * anp[y1*7+x1];
  const float vna = w00 * nap[y0*7+x0] + w01 * nap[y0*7+x1] + w10 * nap[y1*7+x0] + w11 * nap[y1*7+x1];
  bAN[(size_t)blk * NTOK + tid] = van + ah[(size_t)blk * H_ + y] + aw[(size_t)blk * H_ + x];
  bNA[((size_t)h * NTOK + tid) * AG_ + a] =
      vna + ha[((size_t)h * H_ + y) * AG_ + a] + wa[((size_t)h * H_ + x) * AG_ + a];
}

// ---------------------------------------------------------------------------
// Adaptive pool (unchanged, verified)
// ---------------------------------------------------------------------------
__global__ __launch_bounds__(512) void pool_kernel(const u16* __restrict__ qb, u16* __restrict__ agb)
{
  const int blk = blockIdx.x;
  const int b = blk / AG_, a = blk - b * AG_;
  const int o = a / 12, pc = a - o * 12;
  const int y0 = (3 * o) >> 1, x0 = (3 * pc) >> 1;
  const int c = threadIdx.x; const int h = c >> 6, d = c & 63;
  const size_t base = ((size_t)(b * NH_ + h)) * NTOK * HD_ + d;
  const int t00 = (y0 * H_ + x0) * HD_;
  const float v = bfu2f(qb[base + t00]) + bfu2f(qb[base + t00 + HD_])
                + bfu2f(qb[base + t00 + H_ * HD_]) + bfu2f(qb[base + t00 + H_ * HD_ + HD_]);
  agb[((size_t)(b * NH_ + h)) * AG_ * HD_ + a * HD_ + d] = f2bfu(0.25f * v);
}

// ---------------------------------------------------------------------------
// Depthwise 3x3 conv: aob[b][t][h*64+d] = dwc(v). Coalesced; runs before
// stage2 which accumulates attention on top (RMW). NOTE aob aliases kb, so
// this must launch AFTER stage1 (which reads kb).
// ---------------------------------------------------------------------------
__global__ __launch_bounds__(512) void dwc_kernel(
    const u16* __restrict__ vb, const float* __restrict__ dwc_w,
    const float* __restrict__ dwc_b, u16* __restrict__ aob)
{
  __shared__ __align__(16) u16 vL[NTOK * 64];
  const int bh = blockIdx.x, b = bh >> 3, h = bh & 7;
  const int tid = threadIdx.x;
  const bf16x8* vs = (const bf16x8*)(vb + (size_t)bh * NTOK * HD_);
  for (int idx = tid; idx < NTOK * 8; idx += 512)
    ((bf16x8*)vL)[idx] = vs[idx];
  const int d = tid & 63, tg = tid >> 6;
  float w9[9];
  #pragma unroll
  for (int j = 0; j < 9; ++j) w9[j] = dwc_w[(size_t)(h * 64 + d) * 9 + j];
  const float cb = dwc_b[h * 64 + d];
  __syncthreads();
  for (int t = tg; t < NTOK; t += 8) {
    const int y = t / H_, x = t - y * H_;
    float conv = cb;
    #pragma unroll
    for (int ky = 0; ky < 3; ++ky) {
      const int yy = y + ky - 1;
      if (yy < 0 || yy >= H_) continue;
      #pragma unroll
      for (int kx = 0; kx < 3; ++kx) {
        const int xc = x + kx - 1;
        if (xc < 0 || xc >= H_) continue;
        conv += w9[ky * 3 + kx] * bfu2f(vL[(yy * H_ + xc) * 64 + d]);
      }
    }
    aob[((size_t)b * NTOK + t) * C_ + h * 64 + d] = f2bfu(conv);
  }
}

// ---------------------------------------------------------------------------
// Stage 1 v2: S = ag@K^T (K-frags from global), reg softmax, chunked P->LDS
// (per-wave 16x40, no barriers), PV vs vT (stride 360, conflict-free).
// Output written TRANSPOSED: avbT[bh][d][a(160 pad, zeros at 144..159)].
// ---------------------------------------------------------------------------
__global__ __launch_bounds__(576) void stage1_v2(
    const u16* __restrict__ kb, const u16* __restrict__ vb,
    const u16* __restrict__ agb, const float* __restrict__ bAN,
    u16* __restrict__ avbT)
{
  __shared__ __align__(16) u16 vT[64 * 360];
  __shared__ __align__(16) u16 pW[9][16][40];
  const int bh = blockIdx.x, h = bh & 7;
  const int tid = threadIdx.x;

  // zero the agent-pad columns of avbT
  for (int idx = tid; idx < 64 * 16; idx += 576)
    avbT[((size_t)bh * 64 + (idx >> 4)) * 160 + 144 + (idx & 15)] = 0;

  const u16* vsrc = vb + (size_t)bh * NTOK * HD_;
  for (int idx = tid; idx < 64 * 352; idx += 576) {
    const int d = idx & 63, n = idx >> 6;
    vT[d * 360 + n] = (n < NTOK) ? vsrc[n * HD_ + d] : (u16)0;
  }
  __syncthreads();

  const int mt = tid >> 6;        // wave = 16-agent m-tile (0..8)
  const int l  = tid & 63, lr = l & 15, lk = l >> 4;

  const u16* aga = agb + ((size_t)bh * AG_ + mt * 16 + lr) * HD_ + lk * 8;
  const bf16x8 a0 = *(const bf16x8*)(aga);
  const bf16x8 a1 = *(const bf16x8*)(aga + 32);

  f32x4 acc[21];
  const u16* kbase = kb + (size_t)bh * NTOK * HD_ + lk * 8;
  #pragma unroll
  for (int nt = 0; nt < 21; ++nt) {
    const bf16x8 b0 = *(const bf16x8*)(kbase + (size_t)(nt * 16 + lr) * HD_);
    const bf16x8 b1 = *(const bf16x8*)(kbase + (size_t)(nt * 16 + lr) * HD_ + 32);
    f32x4 c = {0.f, 0.f, 0.f, 0.f};
    c = __builtin_amdgcn_mfma_f32_16x16x32_bf16(a0, b0, c, 0, 0, 0);
    c = __builtin_amdgcn_mfma_f32_16x16x32_bf16(a1, b1, c, 0, 0, 0);
    acc[nt] = c;
  }

  const float* bb = bAN + ((size_t)h * AG_ + mt * 16) * NTOK;
  float mx[4] = {-1e30f, -1e30f, -1e30f, -1e30f};
  #pragma unroll
  for (int nt = 0; nt < 21; ++nt) {
    const int col = nt * 16 + lr;
    const bool valid = (nt < 20) || (lr < 4);
    #pragma unroll
    for (int r = 0; r < 4; ++r) {
      float s = -1e30f;
      if (valid) s = acc[nt][r] * SCALE + bb[(lk * 4 + r) * NTOK + col];
      acc[nt][r] = s;
      mx[r] = fmaxf(mx[r], s);
    }
  }
  #pragma unroll
  for (int r = 0; r < 4; ++r) {
    #pragma unroll
    for (int o = 1; o < 16; o <<= 1) mx[r] = fmaxf(mx[r], __shfl_xor(mx[r], o));
  }
  float sm[4] = {0.f, 0.f, 0.f, 0.f};
  #pragma unroll
  for (int nt = 0; nt < 21; ++nt) {
    #pragma unroll
    for (int r = 0; r < 4; ++r) {
      const float e = __expf(acc[nt][r] - mx[r]);
      acc[nt][r] = e;
      sm[r] += e;
    }
  }
  #pragma unroll
  for (int r = 0; r < 4; ++r) {
    #pragma unroll
    for (int o = 1; o < 16; o <<= 1) sm[r] += __shfl_xor(sm[r], o);
    sm[r] = 1.0f / sm[r];
  }

  // chunked PV: 11 chunks of K=32 tokens through per-wave 16x40 buffer
  f32x4 ov[4];
  #pragma unroll
  for (int nt2 = 0; nt2 < 4; ++nt2) ov[nt2] = (f32x4){0.f, 0.f, 0.f, 0.f};
  for (int ks = 0; ks < 11; ++ks) {
    #pragma unroll
    for (int half = 0; half < 2; ++half) {
      const int nt = 2 * ks + half;
      #pragma unroll
      for (int r = 0; r < 4; ++r)
        pW[mt][lk * 4 + r][half * 16 + lr] = (nt < 21) ? f2bfu(acc[nt][r] * sm[r]) : (u16)0;
    }
    const bf16x8 pa = *(const bf16x8*)&pW[mt][lr][lk * 8];
    #pragma unroll
    for (int nt2 = 0; nt2 < 4; ++nt2) {
      const bf16x8 vf = *(const bf16x8*)&vT[(nt2 * 16 + lr) * 360 + ks * 32 + lk * 8];
      ov[nt2] = __builtin_amdgcn_mfma_f32_16x16x32_bf16(pa, vf, ov[nt2], 0, 0, 0);
    }
  }
  #pragma unroll
  for (int nt2 = 0; nt2 < 4; ++nt2) {
    #pragma unroll
    for (int r = 0; r < 4; ++r)
      avbT[((size_t)bh * 64 + nt2 * 16 + lr) * 160 + mt * 16 + lk * 4 + r] = f2bfu(ov[nt2][r]);
  }
}

// ---------------------------------------------------------------------------
// Stage 2 v2: S2 = q@ag^T (frags from global), reg softmax, chunked P (5x32
// agent chunks, per-wave 16x40 LDS), PV B-frags DIRECT from global avbT.
// Epilogue: aob += (RMW over dwc_kernel's output). No barriers at all.
// ---------------------------------------------------------------------------
__global__ __launch_bounds__(512) void stage2_v2(
    const u16* __restrict__ qb, const u16* __restrict__ agb,
    const u16* __restrict__ avbT, const float* __restrict__ bNA,
    u16* __restrict__ aob)
{
  __shared__ __align__(16) u16 pW[8][16][40];
  const int bh = blockIdx.x, b = bh >> 3, h = bh & 7;
  const int tid = threadIdx.x;
  const int wv = tid >> 6, l = tid & 63, lr = l & 15, lk = l >> 4;

  for (int mt = wv; mt < 21; mt += 8) {
    const int arow = min(mt * 16 + lr, NTOK - 1);
    const u16* qa = qb + ((size_t)bh * NTOK + arow) * HD_ + lk * 8;
    const bf16x8 a0 = *(const bf16x8*)(qa);
    const bf16x8 a1 = *(const bf16x8*)(qa + 32);

    f32x4 acc[9];
    #pragma unroll
    for (int nt = 0; nt < 9; ++nt) {
      const u16* bp = agb + ((size_t)bh * AG_ + nt * 16 + lr) * HD_ + lk * 8;
      f32x4 c = {0.f, 0.f, 0.f, 0.f};
      c = __builtin_amdgcn_mfma_f32_16x16x32_bf16(a0, *(const bf16x8*)(bp), c, 0, 0, 0);
      c = __builtin_amdgcn_mfma_f32_16x16x32_bf16(a1, *(const bf16x8*)(bp + 32), c, 0, 0, 0);
      acc[nt] = c;
    }

    float mx[4] = {-1e30f, -1e30f, -1e30f, -1e30f};
    #pragma unroll
    for (int nt = 0; nt < 9; ++nt) {
      #pragma unroll
      for (int r = 0; r < 4; ++r) {
        const int trow = min(mt * 16 + lk * 4 + r, NTOK - 1);
        const float s = acc[nt][r] * SCALE + bNA[((size_t)h * NTOK + trow) * AG_ + nt * 16 + lr];
        acc[nt][r] = s;
        mx[r] = fmaxf(mx[r], s);
      }
    }
    #pragma unroll
    for (int r = 0; r < 4; ++r) {
      #pragma unroll
      for (int o = 1; o < 16; o <<= 1) mx[r] = fmaxf(mx[r], __shfl_xor(mx[r], o));
    }
    float sm[4] = {0.f, 0.f, 0.f, 0.f};
    #pragma unroll
    for (int nt = 0; nt < 9; ++nt) {
      #pragma unroll
      for (int r = 0; r < 4; ++r) {
        const float e = __expf(acc[nt][r] - mx[r]);
        acc[nt][r] = e;
        sm[r] += e;
      }
    }
    #pragma unroll
    for (int r = 0; r < 4; ++r) {
      #pragma unroll
      for (int o = 1; o < 16; o <<= 1) sm[r] += __shfl_xor(sm[r], o);
      sm[r] = 1.0f / sm[r];
    }

    // chunked PV: 5 chunks of K=32 agents; B-frags direct from global avbT
    f32x4 ov[4];
    #pragma unroll
    for (int nt2 = 0; nt2 < 4; ++nt2) ov[nt2] = (f32x4){0.f, 0.f, 0.f, 0.f};
    const u16* avbase = avbT + (size_t)bh * 64 * 160;
    for (int ks = 0; ks < 5; ++ks) {
      #pragma unroll
      for (int half = 0; half < 2; ++half) {
        const int nt = 2 * ks + half;
        #pragma unroll
        for (int r = 0; r < 4; ++r)
          pW[wv][lk * 4 + r][half * 16 + lr] = (nt < 9) ? f2bfu(acc[nt][r] * sm[r]) : (u16)0;
      }
      const bf16x8 pa = *(const bf16x8*)&pW[wv][lr][lk * 8];
      #pragma unroll
      for (int nt2 = 0; nt2 < 4; ++nt2) {
        const bf16x8 vf = *(const bf16x8*)(avbase + (size_t)(nt2 * 16 + lr) * 160 + ks * 32 + lk * 8);
        ov[nt2] = __builtin_amdgcn_mfma_f32_16x16x32_bf16(pa, vf, ov[nt2], 0, 0, 0);
      }
    }

    // RMW epilogue: add attention onto dwc output
    #pragma unroll
    for (int nt2 = 0; nt2 < 4; ++nt2) {
      #pragma unroll
      for (int r = 0; r < 4; ++r) {
        const int t = mt * 16 + lk * 4 + r;
        if (t < NTOK) {
          const size_t o = ((size_t)b * NTOK + t) * C_ + h * 64 + nt2 * 16 + lr;
          aob[o] = f2bfu(bfu2f(aob[o]) + ov[nt2][r]);
        }
      }
    }
  }
}

extern "C" void kernel_launch(void* const* d_in, const int* in_sizes, int n_in,
                              void* d_out, int out_size, void* d_ws, size_t ws_size,
                              hipStream_t stream)
{
  (void)in_sizes; (void)n_in; (void)out_size;
  const float* x      = (const float*)d_in[0];
  const float* qkv_w  = (const float*)d_in[1];
  const float* proj_w = (const float*)d_in[2];
  const float* proj_b = (const float*)d_in[3];
  const float* dwc_w  = (const float*)d_in[4];
  const float* dwc_b  = (const float*)d_in[5];
  const float* an     = (const float*)d_in[6];
  const float* na     = (const float*)d_in[7];
  const float* ah     = (const float*)d_in[8];
  const float* aw     = (const float*)d_in[9];
  const float* ha     = (const float*)d_in[10];
  const float* wa     = (const float*)d_in[11];

  char* ws = (char*)d_ws;
  const size_t QB   = (size_t)B_ * NH_ * NTOK * HD_ * 2;    // 42,467,328
  const size_t AGB  = (size_t)B_ * NH_ * AG_  * HD_ * 2;    // 18,874,368
  const size_t AVTB = (size_t)B_ * NH_ * 64 * 160 * 2;      // 20,971,520
  const size_t BB   = (size_t)NH_ * AG_ * NTOK * 4;         //  1,492,992
  const size_t WQ   = (size_t)1536 * 512 * 2;               //  1,572,864
  const size_t WP   = (size_t)512 * 512 * 2;                //    524,288
  u16* qb    = (u16*)(ws);
  u16* kb    = (u16*)(ws + QB);
  u16* vb    = (u16*)(ws + 2 * QB);
  u16* xp    = (u16*)(ws + 3 * QB);                         // dead after GEMM<0>
  u16* agb   = (u16*)(ws + 3 * QB);                         // overlays xp
  u16* avbT  = (u16*)(ws + 3 * QB + AGB);                   // overlays xp
  float* bAN = (float*)(ws + 3 * QB + AGB + AVTB);          // overlays xp tail
  u16* wqkvT = (u16*)(ws + 4 * QB);
  u16* wprojT= (u16*)(ws + 4 * QB + WQ);
  float* bNA = (float*)(ws + 4 * QB + WQ + WP);
  u16* aob   = kb;                                          // k dead after stage1
  if (ws_size < 4 * QB + WQ + WP + BB) return;

  conv_x   <<<dim3(B_ * NTOK * 64 / 256), dim3(256), 0, stream>>>(x, xp);
  tconv    <<<dim3(8, 24), dim3(256), 0, stream>>>(qkv_w, wqkvT, 1536);
  tconv    <<<dim3(8, 8),  dim3(256), 0, stream>>>(proj_w, wprojT, 512);
  mfma_gemm<0><<<dim3(12, 324), dim3(256), 0, stream>>>(xp, wqkvT, qb, kb, vb, nullptr, nullptr);
  pool_kernel<<<dim3(B_ * AG_),  dim3(512), 0, stream>>>(qb, agb);
  bias_kernel<<<dim3(NH_ * AG_), dim3(324), 0, stream>>>(an, na, ah, aw, ha, wa, bAN, bNA);
  stage1_v2<<<dim3(B_ * NH_),  dim3(576), 0, stream>>>(kb, vb, agb, bAN, avbT);
  dwc_kernel<<<dim3(B_ * NH_), dim3(512), 0, stream>>>(vb, dwc_w, dwc_b, aob);
  stage2_v2<<<dim3(B_ * NH_),  dim3(512), 0, stream>>>(qb, agb, avbT, bNA, aob);
  mfma_gemm<1><<<dim3(4, 320), dim3(256), 0, stream>>>(aob, wprojT, nullptr, nullptr, nullptr, proj_b, (float*)d_out);
}